// Round 1
// baseline (1126.331 us; speedup 1.0000x reference)
//
#include <hip/hip_runtime.h>
#include <math.h>

#define NSRC 50000
#define NDST 50000
#define NE   500000
#define HD   128
#define EDIM 32
#define LN_EPS 1e-5f

// ---------------------------------------------------------------------------
// Fold kernel: Wsm = Wsrc@Wmsg, bsm = bsrc@Wmsg + bmsg,
//              WeMsg = We@Wmsg,  c2 = be@Wmsg
// grid 162 x 128 threads. Row r<128 -> Wsm row; 128..159 -> WeMsg row;
// 160 -> bsm; 161 -> c2.
// ---------------------------------------------------------------------------
__global__ __launch_bounds__(128) void fold_kernel(
    const float* __restrict__ Wsrc, const float* __restrict__ bsrc,
    const float* __restrict__ We,   const float* __restrict__ be,
    const float* __restrict__ Wmsg, const float* __restrict__ bmsg,
    float* __restrict__ Wsm, float* __restrict__ bsm,
    float* __restrict__ WeMsg, float* __restrict__ c2)
{
    const int j = threadIdx.x;
    const int r = blockIdx.x;
    float s = 0.f;
    if (r < 128) {
        for (int k = 0; k < 128; ++k) s += Wsrc[r*HD + k] * Wmsg[k*HD + j];
        Wsm[r*HD + j] = s;
    } else if (r < 160) {
        const int rr = r - 128;
        for (int k = 0; k < 128; ++k) s += We[rr*HD + k] * Wmsg[k*HD + j];
        WeMsg[rr*HD + j] = s;
    } else if (r == 160) {
        for (int k = 0; k < 128; ++k) s += bsrc[k] * Wmsg[k*HD + j];
        bsm[j] = s + bmsg[j];
    } else {
        for (int k = 0; k < 128; ++k) s += be[k] * Wmsg[k*HD + j];
        c2[j] = s;
    }
}

// ---------------------------------------------------------------------------
// gemm128: C[N,128] = A[N,128] @ W[128,128] (+ bias) (+ old C if accum)
// W fully in LDS (64 KB). Block 256 threads -> 32 rows x 128 cols per block.
// Thread (cg = t&31, rg = t>>5): cols 4cg..4cg+3, rows rg*4..rg*4+3.
// A loads are (half-)wave-broadcast float4; W LDS reads conflict-free.
// ---------------------------------------------------------------------------
__global__ __launch_bounds__(256) void gemm128_kernel(
    const float* __restrict__ A, const float* __restrict__ W,
    const float* __restrict__ bias, float* __restrict__ C,
    int N, int accum)
{
    __shared__ float Ws[HD * HD];      // 64 KB
    const int t = threadIdx.x;
    const float4* Wg4 = (const float4*)W;
    float4* Ws4 = (float4*)Ws;
#pragma unroll
    for (int i = 0; i < 16; ++i) Ws4[t + i*256] = Wg4[t + i*256];
    __syncthreads();

    const int cg = t & 31;
    const int rg = t >> 5;
    const int row0 = blockIdx.x * 32 + rg * 4;

    int rowL[4];
#pragma unroll
    for (int rr = 0; rr < 4; ++rr) {
        int r = row0 + rr;
        rowL[rr] = (r < N) ? r : (N - 1);   // clamp; stores are guarded
    }

    float4 b4 = make_float4(0.f, 0.f, 0.f, 0.f);
    if (bias) b4 = ((const float4*)bias)[cg];
    float4 acc[4];
#pragma unroll
    for (int rr = 0; rr < 4; ++rr) acc[rr] = b4;

    const float4* A4 = (const float4*)A;
    float4* C4 = (float4*)C;
    if (accum) {
#pragma unroll
        for (int rr = 0; rr < 4; ++rr) {
            float4 c = C4[rowL[rr]*32 + cg];
            acc[rr].x += c.x; acc[rr].y += c.y; acc[rr].z += c.z; acc[rr].w += c.w;
        }
    }

    for (int k4 = 0; k4 < 32; ++k4) {
        float4 a0 = A4[rowL[0]*32 + k4];
        float4 a1 = A4[rowL[1]*32 + k4];
        float4 a2 = A4[rowL[2]*32 + k4];
        float4 a3 = A4[rowL[3]*32 + k4];
#pragma unroll
        for (int kk = 0; kk < 4; ++kk) {
            float4 w = Ws4[(k4*4 + kk)*32 + cg];
            float f0 = ((const float*)&a0)[kk];
            float f1 = ((const float*)&a1)[kk];
            float f2 = ((const float*)&a2)[kk];
            float f3 = ((const float*)&a3)[kk];
            acc[0].x += f0*w.x; acc[0].y += f0*w.y; acc[0].z += f0*w.z; acc[0].w += f0*w.w;
            acc[1].x += f1*w.x; acc[1].y += f1*w.y; acc[1].z += f1*w.z; acc[1].w += f1*w.w;
            acc[2].x += f2*w.x; acc[2].y += f2*w.y; acc[2].z += f2*w.z; acc[2].w += f2*w.w;
            acc[3].x += f3*w.x; acc[3].y += f3*w.y; acc[3].z += f3*w.z; acc[3].w += f3*w.w;
        }
    }

#pragma unroll
    for (int rr = 0; rr < 4; ++rr) {
        int r = row0 + rr;
        if (r < N) C4[r*32 + cg] = acc[rr];
    }
}

// ---------------------------------------------------------------------------
// tanhdot: sout[n] = sum_j tanh(Y[n,j]) * wa[j]   (wave per row)
// ---------------------------------------------------------------------------
__global__ __launch_bounds__(256) void tanhdot_kernel(
    const float* __restrict__ Y, const float* __restrict__ wa,
    float* __restrict__ sout, int N)
{
    const int lane = threadIdx.x & 63;
    const int n = blockIdx.x * 4 + (threadIdx.x >> 6);
    if (n >= N) return;
    float v = tanhf(Y[n*HD + lane]) * wa[lane]
            + tanhf(Y[n*HD + 64 + lane]) * wa[64 + lane];
#pragma unroll
    for (int off = 32; off; off >>= 1) v += __shfl_down(v, off);
    if (lane == 0) sout[n] = v;
}

// ---------------------------------------------------------------------------
// CSR build
// ---------------------------------------------------------------------------
__global__ void hist_kernel(const int* __restrict__ ei, int* __restrict__ cnt)
{
    int e = blockIdx.x * 256 + threadIdx.x;
    if (e < NE) atomicAdd(&cnt[ei[NE + e]], 1);
}

__global__ __launch_bounds__(1024) void scan_kernel(
    const int* __restrict__ cnt, int* __restrict__ rowptr, int* __restrict__ cursor)
{
    __shared__ int buf[1024];
    __shared__ int carry;
    const int t = threadIdx.x;
    if (t == 0) carry = 0;
    __syncthreads();
    for (int base = 0; base < NDST; base += 1024) {
        int i = base + t;
        int v = (i < NDST) ? cnt[i] : 0;
        buf[t] = v;
        __syncthreads();
        for (int off = 1; off < 1024; off <<= 1) {
            int tv = (t >= off) ? buf[t - off] : 0;
            __syncthreads();
            buf[t] += tv;
            __syncthreads();
        }
        int out = carry + buf[t] - v;          // exclusive prefix + carry
        if (i < NDST) { rowptr[i] = out; cursor[i] = out; }
        int tot = buf[1023];
        __syncthreads();
        if (t == 0) carry += tot;
        __syncthreads();
    }
    if (t == 0) rowptr[NDST] = carry;
}

__global__ void scatter_kernel(const int* __restrict__ ei,
                               int* __restrict__ cursor, int* __restrict__ eids)
{
    int e = blockIdx.x * 256 + threadIdx.x;
    if (e < NE) {
        int pos = atomicAdd(&cursor[ei[NE + e]], 1);
        eids[pos] = e;
    }
}

// ---------------------------------------------------------------------------
// edge_score: one wave per edge-iteration; lane covers cols (lane, lane+64).
// score[e] = s1[src] + s2[dst] + sum_j tanh((ea@We+be)_j) * Wa3_j + battn
// We columns held in registers; ea broadcast via shfl.
// ---------------------------------------------------------------------------
__global__ __launch_bounds__(256) void edge_score_kernel(
    const int* __restrict__ ei, const float* __restrict__ eattr,
    const float* __restrict__ We, const float* __restrict__ be,
    const float* __restrict__ wattn, const float* __restrict__ battn,
    const float* __restrict__ s1, const float* __restrict__ s2,
    float* __restrict__ scores)
{
    const int lane = threadIdx.x & 63;
    const int gw = blockIdx.x * 4 + (threadIdx.x >> 6);
    const int nw = gridDim.x * 4;

    float wL[EDIM], wH[EDIM];
#pragma unroll
    for (int k = 0; k < EDIM; ++k) {
        wL[k] = We[k*HD + lane];
        wH[k] = We[k*HD + 64 + lane];
    }
    const float beL = be[lane], beH = be[64 + lane];
    const float waL = wattn[2*HD + lane], waH = wattn[2*HD + 64 + lane];
    const float b0 = battn[0];

    for (int e = gw; e < NE; e += nw) {
        float ea = eattr[e*EDIM + (lane & 31)];
        float elL = beL, elH = beH;
#pragma unroll
        for (int k = 0; k < EDIM; ++k) {
            float a = __shfl(ea, k);
            elL += a * wL[k];
            elH += a * wH[k];
        }
        float v = tanhf(elL) * waL + tanhf(elH) * waH;
#pragma unroll
        for (int off = 32; off; off >>= 1) v += __shfl_xor(v, off);
        if (lane == 0) {
            int src = ei[e], dst = ei[NE + e];
            scores[e] = v + s1[src] + s2[dst] + b0;
        }
    }
}

// ---------------------------------------------------------------------------
// dst_agg: one wave per dst. Softmax over its CSR edge list (shfl reductions),
// then agg[d] = sum_e alpha_e * (src_msg[src_e] + ea_e@WeMsg + c2).
// ---------------------------------------------------------------------------
__global__ __launch_bounds__(256) void dst_agg_kernel(
    const int* __restrict__ ei, const float* __restrict__ eattr,
    const int* __restrict__ rowptr, const int* __restrict__ eids,
    const float* __restrict__ scores, const float* __restrict__ srcmsg,
    const float* __restrict__ WeMsg, const float* __restrict__ c2,
    float* __restrict__ agg)
{
    const int lane = threadIdx.x & 63;
    const int gw = blockIdx.x * 4 + (threadIdx.x >> 6);
    const int nw = gridDim.x * 4;

    float wL[EDIM], wH[EDIM];
#pragma unroll
    for (int k = 0; k < EDIM; ++k) {
        wL[k] = WeMsg[k*HD + lane];
        wH[k] = WeMsg[k*HD + 64 + lane];
    }
    const float c2L = c2[lane], c2H = c2[64 + lane];

    for (int d = gw; d < NDST; d += nw) {
        const int start = rowptr[d], end = rowptr[d + 1];
        if (start == end) {
            agg[d*HD + lane] = 0.f;
            agg[d*HD + 64 + lane] = 0.f;
            continue;
        }
        float m = -3.4e38f;
        for (int i = start + lane; i < end; i += 64)
            m = fmaxf(m, scores[eids[i]]);
#pragma unroll
        for (int off = 32; off; off >>= 1) m = fmaxf(m, __shfl_xor(m, off));

        float s = 0.f;
        for (int i = start + lane; i < end; i += 64)
            s += expf(scores[eids[i]] - m);
#pragma unroll
        for (int off = 32; off; off >>= 1) s += __shfl_xor(s, off);
        const float inv = 1.f / s;

        float accL = 0.f, accH = 0.f;
        for (int i = start; i < end; ++i) {
            const int e = eids[i];
            const float w = expf(scores[e] - m);
            float ea = eattr[e*EDIM + (lane & 31)];
            float emL = c2L, emH = c2H;
#pragma unroll
            for (int k = 0; k < EDIM; ++k) {
                float a = __shfl(ea, k);
                emL += a * wL[k];
                emH += a * wH[k];
            }
            const int src = ei[e];
            const float* sm = srcmsg + (long long)src * HD;
            accL += w * (sm[lane] + emL);
            accH += w * (sm[64 + lane] + emH);
        }
        agg[d*HD + lane] = accL * inv;
        agg[d*HD + 64 + lane] = accH * inv;
    }
}

// ---------------------------------------------------------------------------
// final layernorm: out = LN(dst_x + upd) * gamma + beta   (wave per row)
// ---------------------------------------------------------------------------
__global__ __launch_bounds__(256) void final_ln_kernel(
    const float* __restrict__ dstx, const float* __restrict__ upd,
    const float* __restrict__ gamma, const float* __restrict__ beta,
    float* __restrict__ out)
{
    const int lane = threadIdx.x & 63;
    const int n = blockIdx.x * 4 + (threadIdx.x >> 6);
    if (n >= NDST) return;
    float hL = dstx[n*HD + lane]      + upd[n*HD + lane];
    float hH = dstx[n*HD + 64 + lane] + upd[n*HD + 64 + lane];
    float s = hL + hH, q = hL*hL + hH*hH;
#pragma unroll
    for (int off = 32; off; off >>= 1) {
        s += __shfl_xor(s, off);
        q += __shfl_xor(q, off);
    }
    const float mean = s * (1.f / HD);
    const float var  = q * (1.f / HD) - mean * mean;
    const float rstd = rsqrtf(var + LN_EPS);
    out[n*HD + lane]      = (hL - mean) * rstd * gamma[lane]      + beta[lane];
    out[n*HD + 64 + lane] = (hH - mean) * rstd * gamma[64 + lane] + beta[64 + lane];
}

// ---------------------------------------------------------------------------
extern "C" void kernel_launch(void* const* d_in, const int* in_sizes, int n_in,
                              void* d_out, int out_size, void* d_ws, size_t ws_size,
                              hipStream_t stream)
{
    const float* src_x = (const float*)d_in[0];
    const float* dst_x = (const float*)d_in[1];
    const int*   ei    = (const int*)d_in[2];      // [2, E] int32: row0=src, row1=dst
    const float* eattr = (const float*)d_in[3];
    const float* Wsrc  = (const float*)d_in[4];
    const float* bsrc  = (const float*)d_in[5];
    const float* Wdst  = (const float*)d_in[6];
    const float* bdst  = (const float*)d_in[7];
    const float* We    = (const float*)d_in[8];
    const float* be    = (const float*)d_in[9];
    const float* Wattn = (const float*)d_in[10];
    const float* battn = (const float*)d_in[11];
    const float* Wmsg  = (const float*)d_in[12];
    const float* bmsg  = (const float*)d_in[13];
    const float* Wout  = (const float*)d_in[14];
    const float* bout  = (const float*)d_in[15];
    const float* gamma = (const float*)d_in[16];
    const float* beta  = (const float*)d_in[17];
    float* out = (float*)d_out;

    // workspace layout (floats)
    float* ws     = (float*)d_ws;
    float* srcmsg = ws;                       // 6,400,000
    float* aggbuf = ws + 6400000;             // 6,400,000 (scratch for src_lin/dst_lin, then agg)
    float* tmp    = ws + 12800000;            // 6,400,000
    float* s1     = ws + 19200000;            // 50,000 (padded 50,048)
    float* s2     = s1 + 50048;               // 50,000 (padded 50,048)
    float* scores = s2 + 50048;               // 500,000
    float* Wsm    = scores + 500000;          // 16,384
    float* bsm    = Wsm + 16384;              // 128
    float* WeMsg  = bsm + 128;                // 4,096
    float* c2     = WeMsg + 4096;             // 128
    int* rowptr   = (int*)(c2 + 128);         // 50,001 (padded 50,016)
    int* cursor   = rowptr + 50016;           // 50,000 (padded 50,016)
    int* eids     = cursor + 50016;           // 500,000

    // zero the histogram/cursor buffer
    hipMemsetAsync(cursor, 0, NDST * sizeof(int), stream);

    // folded weights
    fold_kernel<<<162, 128, 0, stream>>>(Wsrc, bsrc, We, be, Wmsg, bmsg,
                                         Wsm, bsm, WeMsg, c2);

    const int gemmGrid = (NSRC + 31) / 32;    // 1563

    // s1 = dot(tanh(src_x@Wsrc+bsrc), Wa1)
    gemm128_kernel<<<gemmGrid, 256, 0, stream>>>(src_x, Wsrc, bsrc, aggbuf, NSRC, 0);
    tanhdot_kernel<<<(NSRC + 3) / 4, 256, 0, stream>>>(aggbuf, Wattn, s1, NSRC);
    // s2 = dot(tanh(dst_x@Wdst+bdst), Wa2)
    gemm128_kernel<<<gemmGrid, 256, 0, stream>>>(dst_x, Wdst, bdst, aggbuf, NDST, 0);
    tanhdot_kernel<<<(NDST + 3) / 4, 256, 0, stream>>>(aggbuf, Wattn + HD, s2, NDST);
    // src_msg = src_x@(Wsrc@Wmsg) + (bsrc@Wmsg + bmsg)
    gemm128_kernel<<<gemmGrid, 256, 0, stream>>>(src_x, Wsm, bsm, srcmsg, NSRC, 0);

    // CSR by dst
    hist_kernel<<<(NE + 255) / 256, 256, 0, stream>>>(ei, cursor);
    scan_kernel<<<1, 1024, 0, stream>>>(cursor, rowptr, cursor);
    scatter_kernel<<<(NE + 255) / 256, 256, 0, stream>>>(ei, cursor, eids);

    // edge scores
    edge_score_kernel<<<2048, 256, 0, stream>>>(ei, eattr, We, be, Wattn, battn,
                                                s1, s2, scores);
    // softmax + aggregate
    dst_agg_kernel<<<2048, 256, 0, stream>>>(ei, eattr, rowptr, eids, scores,
                                             srcmsg, WeMsg, c2, aggbuf);

    // out = LN(dst_x + dst_x@Wout1 + agg@Wout2 + bout)
    gemm128_kernel<<<gemmGrid, 256, 0, stream>>>(dst_x, Wout, bout, tmp, NDST, 0);
    gemm128_kernel<<<gemmGrid, 256, 0, stream>>>(aggbuf, Wout + HD*HD, nullptr, tmp, NDST, 1);
    final_ln_kernel<<<(NDST + 3) / 4, 256, 0, stream>>>(dst_x, tmp, gamma, beta, out);
}

// Round 2
// 735.248 us; speedup vs baseline: 1.5319x; 1.5319x over previous
//
#include <hip/hip_runtime.h>
#include <math.h>

#define NSRC 50000
#define NDST 50000
#define NE   500000
#define HD   128
#define EDIM 32
#define LN_EPS 1e-5f

__device__ __forceinline__ float fast_tanh(float x) {
    float e = __expf(2.f * x);
    return 1.f - 2.f / (e + 1.f);
}

// ---------------------------------------------------------------------------
// fold1: Wsm = Wsrc@Wmsg, bsm = bsrc@Wmsg + bmsg, WeMsg = We@Wmsg, c2 = be@Wmsg
// ---------------------------------------------------------------------------
__global__ __launch_bounds__(128) void fold1_kernel(
    const float* __restrict__ Wsrc, const float* __restrict__ bsrc,
    const float* __restrict__ We,   const float* __restrict__ be,
    const float* __restrict__ Wmsg, const float* __restrict__ bmsg,
    float* __restrict__ Wsm, float* __restrict__ bsm,
    float* __restrict__ WeMsg, float* __restrict__ c2)
{
    const int j = threadIdx.x;
    const int r = blockIdx.x;
    float s = 0.f;
    if (r < 128) {
        for (int k = 0; k < 128; ++k) s += Wsrc[r*HD + k] * Wmsg[k*HD + j];
        Wsm[r*HD + j] = s;
    } else if (r < 160) {
        const int rr = r - 128;
        for (int k = 0; k < 128; ++k) s += We[rr*HD + k] * Wmsg[k*HD + j];
        WeMsg[rr*HD + j] = s;
    } else if (r == 160) {
        for (int k = 0; k < 128; ++k) s += bsrc[k] * Wmsg[k*HD + j];
        bsm[j] = s + bmsg[j];
    } else {
        for (int k = 0; k < 128; ++k) s += be[k] * Wmsg[k*HD + j];
        c2[j] = s;
    }
}

// ---------------------------------------------------------------------------
// fold2: W3 = WeMsg@Wout2 [32,128]; bias2 = bout + c2@Wout2
// (Wout2 = rows 128..255 of Wout)
// ---------------------------------------------------------------------------
__global__ __launch_bounds__(128) void fold2_kernel(
    const float* __restrict__ WeMsg, const float* __restrict__ c2,
    const float* __restrict__ Wout, const float* __restrict__ bout,
    float* __restrict__ W3, float* __restrict__ bias2)
{
    const int j = threadIdx.x;
    const int r = blockIdx.x;
    const float* Wout2 = Wout + HD*HD;
    float s = 0.f;
    if (r < 32) {
        for (int k = 0; k < 128; ++k) s += WeMsg[r*HD + k] * Wout2[k*HD + j];
        W3[r*HD + j] = s;
    } else {
        for (int k = 0; k < 128; ++k) s += c2[k] * Wout2[k*HD + j];
        bias2[j] = s + bout[j];
    }
}

// ---------------------------------------------------------------------------
// gemm128: C[N,128] = A[N,128] @ W[128,128] (+bias) (+C if accum)
// ---------------------------------------------------------------------------
__global__ __launch_bounds__(256) void gemm128_kernel(
    const float* __restrict__ A, const float* __restrict__ W,
    const float* __restrict__ bias, float* __restrict__ C,
    int N, int accum)
{
    __shared__ float Ws[HD * HD];
    const int t = threadIdx.x;
    const float4* Wg4 = (const float4*)W;
    float4* Ws4 = (float4*)Ws;
#pragma unroll
    for (int i = 0; i < 16; ++i) Ws4[t + i*256] = Wg4[t + i*256];
    __syncthreads();

    const int cg = t & 31;
    const int rg = t >> 5;
    const int row0 = blockIdx.x * 32 + rg * 4;

    int rowL[4];
#pragma unroll
    for (int rr = 0; rr < 4; ++rr) {
        int r = row0 + rr;
        rowL[rr] = (r < N) ? r : (N - 1);
    }

    float4 b4 = make_float4(0.f, 0.f, 0.f, 0.f);
    if (bias) b4 = ((const float4*)bias)[cg];
    float4 acc[4];
#pragma unroll
    for (int rr = 0; rr < 4; ++rr) acc[rr] = b4;

    const float4* A4 = (const float4*)A;
    float4* C4 = (float4*)C;
    if (accum) {
#pragma unroll
        for (int rr = 0; rr < 4; ++rr) {
            float4 c = C4[rowL[rr]*32 + cg];
            acc[rr].x += c.x; acc[rr].y += c.y; acc[rr].z += c.z; acc[rr].w += c.w;
        }
    }

    for (int k4 = 0; k4 < 32; ++k4) {
        float4 a0 = A4[rowL[0]*32 + k4];
        float4 a1 = A4[rowL[1]*32 + k4];
        float4 a2 = A4[rowL[2]*32 + k4];
        float4 a3 = A4[rowL[3]*32 + k4];
#pragma unroll
        for (int kk = 0; kk < 4; ++kk) {
            float4 w = Ws4[(k4*4 + kk)*32 + cg];
            float f0 = ((const float*)&a0)[kk];
            float f1 = ((const float*)&a1)[kk];
            float f2 = ((const float*)&a2)[kk];
            float f3 = ((const float*)&a3)[kk];
            acc[0].x += f0*w.x; acc[0].y += f0*w.y; acc[0].z += f0*w.z; acc[0].w += f0*w.w;
            acc[1].x += f1*w.x; acc[1].y += f1*w.y; acc[1].z += f1*w.z; acc[1].w += f1*w.w;
            acc[2].x += f2*w.x; acc[2].y += f2*w.y; acc[2].z += f2*w.z; acc[2].w += f2*w.w;
            acc[3].x += f3*w.x; acc[3].y += f3*w.y; acc[3].z += f3*w.z; acc[3].w += f3*w.w;
        }
    }

#pragma unroll
    for (int rr = 0; rr < 4; ++rr) {
        int r = row0 + rr;
        if (r < N) C4[r*32 + cg] = acc[rr];
    }
}

// ---------------------------------------------------------------------------
// gemm_tanhdot: sout[n] = sum_j tanh((A@W+b)[n,j]) * wa[j]
// same tiling as gemm128, fused tanh-dot epilogue (no [N,128] materialized)
// ---------------------------------------------------------------------------
__global__ __launch_bounds__(256) void gemm_tanhdot_kernel(
    const float* __restrict__ A, const float* __restrict__ W,
    const float* __restrict__ bias, const float* __restrict__ wa,
    float* __restrict__ sout, int N)
{
    __shared__ float Ws[HD * HD];
    const int t = threadIdx.x;
    const float4* Wg4 = (const float4*)W;
    float4* Ws4 = (float4*)Ws;
#pragma unroll
    for (int i = 0; i < 16; ++i) Ws4[t + i*256] = Wg4[t + i*256];
    __syncthreads();

    const int cg = t & 31;
    const int rg = t >> 5;
    const int row0 = blockIdx.x * 32 + rg * 4;

    int rowL[4];
#pragma unroll
    for (int rr = 0; rr < 4; ++rr) {
        int r = row0 + rr;
        rowL[rr] = (r < N) ? r : (N - 1);
    }

    float4 b4 = ((const float4*)bias)[cg];
    float4 acc[4];
#pragma unroll
    for (int rr = 0; rr < 4; ++rr) acc[rr] = b4;

    const float4* A4 = (const float4*)A;
    for (int k4 = 0; k4 < 32; ++k4) {
        float4 a0 = A4[rowL[0]*32 + k4];
        float4 a1 = A4[rowL[1]*32 + k4];
        float4 a2 = A4[rowL[2]*32 + k4];
        float4 a3 = A4[rowL[3]*32 + k4];
#pragma unroll
        for (int kk = 0; kk < 4; ++kk) {
            float4 w = Ws4[(k4*4 + kk)*32 + cg];
            float f0 = ((const float*)&a0)[kk];
            float f1 = ((const float*)&a1)[kk];
            float f2 = ((const float*)&a2)[kk];
            float f3 = ((const float*)&a3)[kk];
            acc[0].x += f0*w.x; acc[0].y += f0*w.y; acc[0].z += f0*w.z; acc[0].w += f0*w.w;
            acc[1].x += f1*w.x; acc[1].y += f1*w.y; acc[1].z += f1*w.z; acc[1].w += f1*w.w;
            acc[2].x += f2*w.x; acc[2].y += f2*w.y; acc[2].z += f2*w.z; acc[2].w += f2*w.w;
            acc[3].x += f3*w.x; acc[3].y += f3*w.y; acc[3].z += f3*w.z; acc[3].w += f3*w.w;
        }
    }

    const float4 wa4 = ((const float4*)wa)[cg];
    float v[4];
#pragma unroll
    for (int rr = 0; rr < 4; ++rr) {
        v[rr] = fast_tanh(acc[rr].x)*wa4.x + fast_tanh(acc[rr].y)*wa4.y
              + fast_tanh(acc[rr].z)*wa4.z + fast_tanh(acc[rr].w)*wa4.w;
    }
#pragma unroll
    for (int off = 16; off; off >>= 1) {
#pragma unroll
        for (int rr = 0; rr < 4; ++rr) v[rr] += __shfl_xor(v[rr], off);
    }
    if (cg == 0) {
#pragma unroll
        for (int rr = 0; rr < 4; ++rr) {
            int r = row0 + rr;
            if (r < N) sout[r] = v[rr];
        }
    }
}

// ---------------------------------------------------------------------------
// gemm32_acc: C[N,128] += A[N,32] @ W[32,128]
// ---------------------------------------------------------------------------
__global__ __launch_bounds__(256) void gemm32_acc_kernel(
    const float* __restrict__ A, const float* __restrict__ W,
    float* __restrict__ C, int N)
{
    __shared__ float Ws[EDIM * HD];   // 16 KB
    const int t = threadIdx.x;
    const float4* Wg4 = (const float4*)W;
    float4* Ws4 = (float4*)Ws;
#pragma unroll
    for (int i = 0; i < 4; ++i) Ws4[t + i*256] = Wg4[t + i*256];
    __syncthreads();

    const int cg = t & 31;
    const int rg = t >> 5;
    const int row0 = blockIdx.x * 32 + rg * 4;

    int rowL[4];
#pragma unroll
    for (int rr = 0; rr < 4; ++rr) {
        int r = row0 + rr;
        rowL[rr] = (r < N) ? r : (N - 1);
    }

    float4* C4 = (float4*)C;
    float4 acc[4];
#pragma unroll
    for (int rr = 0; rr < 4; ++rr) acc[rr] = C4[rowL[rr]*32 + cg];

    const float4* A4 = (const float4*)A;
#pragma unroll
    for (int k4 = 0; k4 < 8; ++k4) {
        float4 a0 = A4[rowL[0]*8 + k4];
        float4 a1 = A4[rowL[1]*8 + k4];
        float4 a2 = A4[rowL[2]*8 + k4];
        float4 a3 = A4[rowL[3]*8 + k4];
#pragma unroll
        for (int kk = 0; kk < 4; ++kk) {
            float4 w = Ws4[(k4*4 + kk)*32 + cg];
            float f0 = ((const float*)&a0)[kk];
            float f1 = ((const float*)&a1)[kk];
            float f2 = ((const float*)&a2)[kk];
            float f3 = ((const float*)&a3)[kk];
            acc[0].x += f0*w.x; acc[0].y += f0*w.y; acc[0].z += f0*w.z; acc[0].w += f0*w.w;
            acc[1].x += f1*w.x; acc[1].y += f1*w.y; acc[1].z += f1*w.z; acc[1].w += f1*w.w;
            acc[2].x += f2*w.x; acc[2].y += f2*w.y; acc[2].z += f2*w.z; acc[2].w += f2*w.w;
            acc[3].x += f3*w.x; acc[3].y += f3*w.y; acc[3].z += f3*w.z; acc[3].w += f3*w.w;
        }
    }

#pragma unroll
    for (int rr = 0; rr < 4; ++rr) {
        int r = row0 + rr;
        if (r < N) C4[r*32 + cg] = acc[rr];
    }
}

// ---------------------------------------------------------------------------
// CSR build
// ---------------------------------------------------------------------------
__global__ void hist_kernel(const int* __restrict__ ei, int* __restrict__ cnt)
{
    int e = blockIdx.x * 256 + threadIdx.x;
    if (e < NE) atomicAdd(&cnt[ei[NE + e]], 1);
}

__global__ __launch_bounds__(1024) void scan_kernel(
    const int* __restrict__ cnt, int* __restrict__ rowptr, int* __restrict__ cursor)
{
    __shared__ int buf[1024];
    __shared__ int carry;
    const int t = threadIdx.x;
    if (t == 0) carry = 0;
    __syncthreads();
    for (int base = 0; base < NDST; base += 1024) {
        int i = base + t;
        int v = (i < NDST) ? cnt[i] : 0;
        buf[t] = v;
        __syncthreads();
        for (int off = 1; off < 1024; off <<= 1) {
            int tv = (t >= off) ? buf[t - off] : 0;
            __syncthreads();
            buf[t] += tv;
            __syncthreads();
        }
        int out = carry + buf[t] - v;
        if (i < NDST) { rowptr[i] = out; cursor[i] = out; }
        int tot = buf[1023];
        __syncthreads();
        if (t == 0) carry += tot;
        __syncthreads();
    }
    if (t == 0) rowptr[NDST] = carry;
}

__global__ void scatter_kernel(const int* __restrict__ ei,
                               int* __restrict__ cursor, int* __restrict__ eids)
{
    int e = blockIdx.x * 256 + threadIdx.x;
    if (e < NE) {
        int pos = atomicAdd(&cursor[ei[NE + e]], 1);
        eids[pos] = e;
    }
}

// ---------------------------------------------------------------------------
// edge_score_fused: tiled GEMM [64 edges x 128] @ K=32 with fused
// tanh-dot(Wa3) epilogue + s1[src] + s2[dst] + battn -> scores[e]
// ---------------------------------------------------------------------------
__global__ __launch_bounds__(256) void edge_score_fused_kernel(
    const int* __restrict__ ei, const float* __restrict__ eattr,
    const float* __restrict__ We, const float* __restrict__ be,
    const float* __restrict__ wattn, const float* __restrict__ battn,
    const float* __restrict__ s1, const float* __restrict__ s2,
    float* __restrict__ scores)
{
    __shared__ float eaS[64 * EDIM];   // 8 KB
    __shared__ float WeS[EDIM * HD];   // 16 KB
    const int t = threadIdx.x;
    const int e0 = blockIdx.x * 64;

    float4* eaS4 = (float4*)eaS;
    const float4* ea_g4 = (const float4*)eattr + (size_t)e0 * 8;
#pragma unroll
    for (int i = 0; i < 2; ++i) {
        int idx = t + i * 256;                 // 0..511
        int e = e0 + (idx >> 3);
        eaS4[idx] = (e < NE) ? ea_g4[idx] : make_float4(0.f, 0.f, 0.f, 0.f);
    }
    float4* WeS4 = (float4*)WeS;
    const float4* We_g4 = (const float4*)We;
#pragma unroll
    for (int i = 0; i < 4; ++i) WeS4[t + i*256] = We_g4[t + i*256];
    __syncthreads();

    const int cg = t & 31;
    const int rg = t >> 5;                     // 0..7, rows rg*8..rg*8+7

    const float4 b4 = ((const float4*)be)[cg];
    float4 acc[8];
#pragma unroll
    for (int r = 0; r < 8; ++r) acc[r] = b4;

#pragma unroll
    for (int k4 = 0; k4 < 8; ++k4) {
        float4 w[4];
#pragma unroll
        for (int kk = 0; kk < 4; ++kk) w[kk] = WeS4[(k4*4 + kk)*32 + cg];
#pragma unroll
        for (int r = 0; r < 8; ++r) {
            float4 a = eaS4[(rg*8 + r)*8 + k4];
            acc[r].x += a.x*w[0].x + a.y*w[1].x + a.z*w[2].x + a.w*w[3].x;
            acc[r].y += a.x*w[0].y + a.y*w[1].y + a.z*w[2].y + a.w*w[3].y;
            acc[r].z += a.x*w[0].z + a.y*w[1].z + a.z*w[2].z + a.w*w[3].z;
            acc[r].w += a.x*w[0].w + a.y*w[1].w + a.z*w[2].w + a.w*w[3].w;
        }
    }

    const float4 wa4 = ((const float4*)(wattn + 2*HD))[cg];
    const float b0 = battn[0];
    float v[8];
#pragma unroll
    for (int r = 0; r < 8; ++r) {
        v[r] = fast_tanh(acc[r].x)*wa4.x + fast_tanh(acc[r].y)*wa4.y
             + fast_tanh(acc[r].z)*wa4.z + fast_tanh(acc[r].w)*wa4.w;
    }
#pragma unroll
    for (int off = 16; off; off >>= 1) {
#pragma unroll
        for (int r = 0; r < 8; ++r) v[r] += __shfl_xor(v[r], off);
    }
    if (cg == 0) {
#pragma unroll
        for (int r = 0; r < 8; ++r) {
            int e = e0 + rg*8 + r;
            if (e < NE) {
                int s = ei[e], d = ei[NE + e];
                scores[e] = v[r] + s1[s] + s2[d] + b0;
            }
        }
    }
}

// ---------------------------------------------------------------------------
// dst_agg2: wave per dst. Softmax over CSR list; aggS[d] = sum alpha*srcmsg[src];
// wea[d] = sum alpha*ea (32-dim). Empty dst: aggS = -c2 (cancels folded bias).
// ---------------------------------------------------------------------------
__global__ __launch_bounds__(256) void dst_agg2_kernel(
    const int* __restrict__ ei, const float* __restrict__ eattr,
    const int* __restrict__ rowptr, const int* __restrict__ eids,
    const float* __restrict__ scores, const float* __restrict__ srcmsg,
    const float* __restrict__ c2,
    float* __restrict__ aggS, float* __restrict__ wea)
{
    const int lane = threadIdx.x & 63;
    const int gw = blockIdx.x * 4 + (threadIdx.x >> 6);
    const int nw = gridDim.x * 4;

    for (int d = gw; d < NDST; d += nw) {
        const int start = rowptr[d], end = rowptr[d + 1];
        if (start == end) {
            aggS[d*HD + lane]      = -c2[lane];
            aggS[d*HD + 64 + lane] = -c2[64 + lane];
            if (lane < EDIM) wea[d*EDIM + lane] = 0.f;
            continue;
        }
        float m = -3.4e38f;
        for (int i = start + lane; i < end; i += 64)
            m = fmaxf(m, scores[eids[i]]);
#pragma unroll
        for (int off = 32; off; off >>= 1) m = fmaxf(m, __shfl_xor(m, off));

        float s = 0.f;
        for (int i = start + lane; i < end; i += 64)
            s += __expf(scores[eids[i]] - m);
#pragma unroll
        for (int off = 32; off; off >>= 1) s += __shfl_xor(s, off);
        const float inv = 1.f / s;

        float accL = 0.f, accH = 0.f, weaAcc = 0.f;
        for (int i = start; i < end; ++i) {
            const int e = eids[i];
            const float w = __expf(scores[e] - m);
            const int src = ei[e];
            const float* sm = srcmsg + (size_t)src * HD;
            accL += w * sm[lane];
            accH += w * sm[64 + lane];
            if (lane < EDIM) weaAcc += w * eattr[(size_t)e * EDIM + lane];
        }
        aggS[d*HD + lane]      = accL * inv;
        aggS[d*HD + 64 + lane] = accH * inv;
        if (lane < EDIM) wea[d*EDIM + lane] = weaAcc * inv;
    }
}

// ---------------------------------------------------------------------------
// final layernorm: out = LN(dst_x + upd) * gamma + beta   (wave per row)
// ---------------------------------------------------------------------------
__global__ __launch_bounds__(256) void final_ln_kernel(
    const float* __restrict__ dstx, const float* __restrict__ upd,
    const float* __restrict__ gamma, const float* __restrict__ beta,
    float* __restrict__ out)
{
    const int lane = threadIdx.x & 63;
    const int n = blockIdx.x * 4 + (threadIdx.x >> 6);
    if (n >= NDST) return;
    float hL = dstx[n*HD + lane]      + upd[n*HD + lane];
    float hH = dstx[n*HD + 64 + lane] + upd[n*HD + 64 + lane];
    float s = hL + hH, q = hL*hL + hH*hH;
#pragma unroll
    for (int off = 32; off; off >>= 1) {
        s += __shfl_xor(s, off);
        q += __shfl_xor(q, off);
    }
    const float mean = s * (1.f / HD);
    const float var  = q * (1.f / HD) - mean * mean;
    const float rstd = rsqrtf(var + LN_EPS);
    out[n*HD + lane]      = (hL - mean) * rstd * gamma[lane]      + beta[lane];
    out[n*HD + 64 + lane] = (hH - mean) * rstd * gamma[64 + lane] + beta[64 + lane];
}

// ---------------------------------------------------------------------------
extern "C" void kernel_launch(void* const* d_in, const int* in_sizes, int n_in,
                              void* d_out, int out_size, void* d_ws, size_t ws_size,
                              hipStream_t stream)
{
    const float* src_x = (const float*)d_in[0];
    const float* dst_x = (const float*)d_in[1];
    const int*   ei    = (const int*)d_in[2];      // [2,E] int32
    const float* eattr = (const float*)d_in[3];
    const float* Wsrc  = (const float*)d_in[4];
    const float* bsrc  = (const float*)d_in[5];
    const float* Wdst  = (const float*)d_in[6];
    const float* bdst  = (const float*)d_in[7];
    const float* We    = (const float*)d_in[8];
    const float* be    = (const float*)d_in[9];
    const float* Wattn = (const float*)d_in[10];
    const float* battn = (const float*)d_in[11];
    const float* Wmsg  = (const float*)d_in[12];
    const float* bmsg  = (const float*)d_in[13];
    const float* Wout  = (const float*)d_in[14];
    const float* bout  = (const float*)d_in[15];
    const float* gamma = (const float*)d_in[16];
    const float* beta  = (const float*)d_in[17];
    float* out = (float*)d_out;

    // workspace layout (floats); tmp aliases srcmsg (dead after dst_agg2)
    float* ws     = (float*)d_ws;
    float* srcmsg = ws;                        // 6,400,000
    float* tmp    = ws;                        // alias
    float* aggS   = ws + 6400000;              // 6,400,000
    float* wea    = ws + 12800000;             // 1,600,000
    float* s1     = ws + 14400000;             // 50,048
    float* s2     = ws + 14450048;             // 50,048
    float* scores = ws + 14500096;             // 500,000
    float* Wsm    = ws + 15000096;             // 16,384
    float* bsm    = ws + 15016480;             // 128
    float* WeMsg  = ws + 15016608;             // 4,096
    float* c2     = ws + 15020704;             // 128
    float* W3     = ws + 15020832;             // 4,096
    float* bias2  = ws + 15024928;             // 128
    int* rowptr   = (int*)(ws + 15025056);     // 50,016
    int* cursor   = rowptr + 50016;            // 50,016
    int* eids     = cursor + 50016;            // 500,000

    hipMemsetAsync(cursor, 0, NDST * sizeof(int), stream);

    fold1_kernel<<<162, 128, 0, stream>>>(Wsrc, bsrc, We, be, Wmsg, bmsg,
                                          Wsm, bsm, WeMsg, c2);
    fold2_kernel<<<33, 128, 0, stream>>>(WeMsg, c2, Wout, bout, W3, bias2);

    const int gemmGrid = (NSRC + 31) / 32;     // 1563

    gemm_tanhdot_kernel<<<gemmGrid, 256, 0, stream>>>(src_x, Wsrc, bsrc, Wattn, s1, NSRC);
    gemm_tanhdot_kernel<<<gemmGrid, 256, 0, stream>>>(dst_x, Wdst, bdst, Wattn + HD, s2, NDST);
    gemm128_kernel<<<gemmGrid, 256, 0, stream>>>(src_x, Wsm, bsm, srcmsg, NSRC, 0);

    hist_kernel<<<(NE + 255) / 256, 256, 0, stream>>>(ei, cursor);
    scan_kernel<<<1, 1024, 0, stream>>>(cursor, rowptr, cursor);
    scatter_kernel<<<(NE + 255) / 256, 256, 0, stream>>>(ei, cursor, eids);

    edge_score_fused_kernel<<<(NE + 63) / 64, 256, 0, stream>>>(
        ei, eattr, We, be, Wattn, battn, s1, s2, scores);

    dst_agg2_kernel<<<3125, 256, 0, stream>>>(ei, eattr, rowptr, eids, scores,
                                              srcmsg, c2, aggS, wea);

    gemm128_kernel<<<gemmGrid, 256, 0, stream>>>(dst_x, Wout, bias2, tmp, NDST, 0);
    gemm128_kernel<<<gemmGrid, 256, 0, stream>>>(aggS, Wout + HD*HD, nullptr, tmp, NDST, 1);
    gemm32_acc_kernel<<<gemmGrid, 256, 0, stream>>>(wea, W3, tmp, NDST);

    final_ln_kernel<<<(NDST + 3) / 4, 256, 0, stream>>>(dst_x, tmp, gamma, beta, out);
}

// Round 3
// 689.983 us; speedup vs baseline: 1.6324x; 1.0656x over previous
//
#include <hip/hip_runtime.h>
#include <math.h>

#define NSRC 50000
#define NDST 50000
#define NE   500000
#define HD   128
#define EDIM 32
#define LN_EPS 1e-5f

__device__ __forceinline__ float fast_tanh(float x) {
    float e = __expf(2.f * x);
    return 1.f - 2.f / (e + 1.f);
}

// ---------------------------------------------------------------------------
// fold1: Wsm = Wsrc@Wmsg, bsm = bsrc@Wmsg + bmsg, WeMsg = We@Wmsg, c2 = be@Wmsg
// ---------------------------------------------------------------------------
__global__ __launch_bounds__(128) void fold1_kernel(
    const float* __restrict__ Wsrc, const float* __restrict__ bsrc,
    const float* __restrict__ We,   const float* __restrict__ be,
    const float* __restrict__ Wmsg, const float* __restrict__ bmsg,
    float* __restrict__ Wsm, float* __restrict__ bsm,
    float* __restrict__ WeMsg, float* __restrict__ c2)
{
    const int j = threadIdx.x;
    const int r = blockIdx.x;
    float s = 0.f;
    if (r < 128) {
        for (int k = 0; k < 128; ++k) s += Wsrc[r*HD + k] * Wmsg[k*HD + j];
        Wsm[r*HD + j] = s;
    } else if (r < 160) {
        const int rr = r - 128;
        for (int k = 0; k < 128; ++k) s += We[rr*HD + k] * Wmsg[k*HD + j];
        WeMsg[rr*HD + j] = s;
    } else if (r == 160) {
        for (int k = 0; k < 128; ++k) s += bsrc[k] * Wmsg[k*HD + j];
        bsm[j] = s + bmsg[j];
    } else {
        for (int k = 0; k < 128; ++k) s += be[k] * Wmsg[k*HD + j];
        c2[j] = s;
    }
}

// ---------------------------------------------------------------------------
// fold2: W3 = WeMsg@Wout2 [32,128]; bias2 = bout + c2@Wout2;
//        Wout1p = Wout1 + I  (residual folded into output projection)
// ---------------------------------------------------------------------------
__global__ __launch_bounds__(128) void fold2_kernel(
    const float* __restrict__ WeMsg, const float* __restrict__ c2,
    const float* __restrict__ Wout, const float* __restrict__ bout,
    float* __restrict__ W3, float* __restrict__ bias2,
    float* __restrict__ Wout1p)
{
    const int j = threadIdx.x;
    const int r = blockIdx.x;
    const float* Wout2 = Wout + HD*HD;
    if (r < 32) {
        float s = 0.f;
        for (int k = 0; k < 128; ++k) s += WeMsg[r*HD + k] * Wout2[k*HD + j];
        W3[r*HD + j] = s;
    } else if (r == 32) {
        float s = 0.f;
        for (int k = 0; k < 128; ++k) s += c2[k] * Wout2[k*HD + j];
        bias2[j] = s + bout[j];
    } else {
        const int rr = r - 33;
        Wout1p[rr*HD + j] = Wout[rr*HD + j] + ((rr == j) ? 1.f : 0.f);
    }
}

// ---------------------------------------------------------------------------
// gemm128_v3: C[N,128] = A[N,128]@W[128,128] (+bias) (+C if accum)
// 256 thr, 64 rows/block, 8x4 micro-tile, K-slabs of 32, A+W staged in LDS.
// LDS = 8KB (A slab) + 16KB (W slab) = 24KB.
// ---------------------------------------------------------------------------
__global__ __launch_bounds__(256) void gemm128_v3_kernel(
    const float* __restrict__ A, const float* __restrict__ W,
    const float* __restrict__ bias, float* __restrict__ C,
    int N, int accum)
{
    __shared__ float As[64 * 32];
    __shared__ float Wsl[32 * HD];
    const int t = threadIdx.x;
    const int cg = t & 31;                 // col f4 index 0..31
    const int rg = t >> 5;                 // row group 0..7, 8 rows each
    const int row0 = blockIdx.x * 64;
    float4* As4 = (float4*)As;
    float4* Wsl4 = (float4*)Wsl;
    const float4* Ag4 = (const float4*)A;
    const float4* Wg4 = (const float4*)W;
    float4* C4 = (float4*)C;
    const int maxAf4 = N * 32;

    float4 acc[8];
    float4 b4 = make_float4(0.f, 0.f, 0.f, 0.f);
    if (bias) b4 = ((const float4*)bias)[cg];
#pragma unroll
    for (int rr = 0; rr < 8; ++rr) acc[rr] = b4;
    if (accum) {
#pragma unroll
        for (int rr = 0; rr < 8; ++rr) {
            int r = row0 + rg*8 + rr;
            r = (r < N) ? r : (N - 1);
            float4 c = C4[r*32 + cg];
            acc[rr].x += c.x; acc[rr].y += c.y; acc[rr].z += c.z; acc[rr].w += c.w;
        }
    }

    for (int s = 0; s < 4; ++s) {
        __syncthreads();
#pragma unroll
        for (int i = 0; i < 2; ++i) {
            int idx = t + i*256;           // row*8 + k4
            int row = idx >> 3, k4 = idx & 7;
            int g = (row0 + row)*32 + s*8 + k4;
            As4[idx] = (g < maxAf4) ? Ag4[g] : make_float4(0.f,0.f,0.f,0.f);
        }
#pragma unroll
        for (int i = 0; i < 4; ++i) {
            int idx = t + i*256;
            Wsl4[idx] = Wg4[s*1024 + idx];
        }
        __syncthreads();
#pragma unroll
        for (int k4 = 0; k4 < 8; ++k4) {
            float4 w[4];
#pragma unroll
            for (int kk = 0; kk < 4; ++kk) w[kk] = Wsl4[(k4*4 + kk)*32 + cg];
#pragma unroll
            for (int rr = 0; rr < 8; ++rr) {
                float4 a = As4[(rg*8 + rr)*8 + k4];
                acc[rr].x += a.x*w[0].x + a.y*w[1].x + a.z*w[2].x + a.w*w[3].x;
                acc[rr].y += a.x*w[0].y + a.y*w[1].y + a.z*w[2].y + a.w*w[3].y;
                acc[rr].z += a.x*w[0].z + a.y*w[1].z + a.z*w[2].z + a.w*w[3].z;
                acc[rr].w += a.x*w[0].w + a.y*w[1].w + a.z*w[2].w + a.w*w[3].w;
            }
        }
    }

#pragma unroll
    for (int rr = 0; rr < 8; ++rr) {
        int r = row0 + rg*8 + rr;
        if (r < N) C4[r*32 + cg] = acc[rr];
    }
}

// ---------------------------------------------------------------------------
// gemm_td_v3: sout[n] = sum_j tanh((A@W+b)[n,j]) * wa[j]  — same tiling,
// fused tanh-dot epilogue.
// ---------------------------------------------------------------------------
__global__ __launch_bounds__(256) void gemm_td_v3_kernel(
    const float* __restrict__ A, const float* __restrict__ W,
    const float* __restrict__ bias, const float* __restrict__ wa,
    float* __restrict__ sout, int N)
{
    __shared__ float As[64 * 32];
    __shared__ float Wsl[32 * HD];
    const int t = threadIdx.x;
    const int cg = t & 31;
    const int rg = t >> 5;
    const int row0 = blockIdx.x * 64;
    float4* As4 = (float4*)As;
    float4* Wsl4 = (float4*)Wsl;
    const float4* Ag4 = (const float4*)A;
    const float4* Wg4 = (const float4*)W;
    const int maxAf4 = N * 32;

    float4 b4 = ((const float4*)bias)[cg];
    float4 acc[8];
#pragma unroll
    for (int rr = 0; rr < 8; ++rr) acc[rr] = b4;

    for (int s = 0; s < 4; ++s) {
        __syncthreads();
#pragma unroll
        for (int i = 0; i < 2; ++i) {
            int idx = t + i*256;
            int row = idx >> 3, k4 = idx & 7;
            int g = (row0 + row)*32 + s*8 + k4;
            As4[idx] = (g < maxAf4) ? Ag4[g] : make_float4(0.f,0.f,0.f,0.f);
        }
#pragma unroll
        for (int i = 0; i < 4; ++i) {
            int idx = t + i*256;
            Wsl4[idx] = Wg4[s*1024 + idx];
        }
        __syncthreads();
#pragma unroll
        for (int k4 = 0; k4 < 8; ++k4) {
            float4 w[4];
#pragma unroll
            for (int kk = 0; kk < 4; ++kk) w[kk] = Wsl4[(k4*4 + kk)*32 + cg];
#pragma unroll
            for (int rr = 0; rr < 8; ++rr) {
                float4 a = As4[(rg*8 + rr)*8 + k4];
                acc[rr].x += a.x*w[0].x + a.y*w[1].x + a.z*w[2].x + a.w*w[3].x;
                acc[rr].y += a.x*w[0].y + a.y*w[1].y + a.z*w[2].y + a.w*w[3].y;
                acc[rr].z += a.x*w[0].z + a.y*w[1].z + a.z*w[2].z + a.w*w[3].z;
                acc[rr].w += a.x*w[0].w + a.y*w[1].w + a.z*w[2].w + a.w*w[3].w;
            }
        }
    }

    const float4 wa4 = ((const float4*)wa)[cg];
    float v[8];
#pragma unroll
    for (int rr = 0; rr < 8; ++rr) {
        v[rr] = fast_tanh(acc[rr].x)*wa4.x + fast_tanh(acc[rr].y)*wa4.y
              + fast_tanh(acc[rr].z)*wa4.z + fast_tanh(acc[rr].w)*wa4.w;
    }
#pragma unroll
    for (int off = 16; off; off >>= 1) {
#pragma unroll
        for (int rr = 0; rr < 8; ++rr) v[rr] += __shfl_xor(v[rr], off);
    }
    if (cg == 0) {
#pragma unroll
        for (int rr = 0; rr < 8; ++rr) {
            int r = row0 + rg*8 + rr;
            if (r < N) sout[r] = v[rr];
        }
    }
}

// ---------------------------------------------------------------------------
// CSR build: hist + two-level scan + scatter
// ---------------------------------------------------------------------------
__global__ void hist_kernel(const int* __restrict__ ei, int* __restrict__ cnt)
{
    int e = blockIdx.x * 256 + threadIdx.x;
    if (e < NE) atomicAdd(&cnt[ei[NE + e]], 1);
}

__global__ __launch_bounds__(1024) void scan1_kernel(
    const int* __restrict__ cnt, int* __restrict__ excl, int* __restrict__ bsum)
{
    __shared__ int buf[1024];
    const int t = threadIdx.x;
    const int i = blockIdx.x * 1024 + t;
    int v = (i < NDST) ? cnt[i] : 0;
    buf[t] = v;
    __syncthreads();
    for (int off = 1; off < 1024; off <<= 1) {
        int tv = (t >= off) ? buf[t - off] : 0;
        __syncthreads();
        buf[t] += tv;
        __syncthreads();
    }
    if (i < NDST) excl[i] = buf[t] - v;
    if (t == 1023) bsum[blockIdx.x] = buf[1023];
}

__global__ void scan2_kernel(int* __restrict__ bsum, int* __restrict__ rowptr)
{
    const int NB = (NDST + 1023) / 1024;   // 49
    const int t = threadIdx.x;             // 64 threads
    int orig = (t < NB) ? bsum[t] : 0;
    int v = orig;
    for (int off = 1; off < 64; off <<= 1) {
        int u = __shfl_up(v, off);
        if (t >= off) v += u;
    }
    int total = __shfl(v, 63);
    if (t < NB) bsum[t] = v - orig;        // exclusive
    if (t == 0) rowptr[NDST] = total;
}

__global__ void scan3_kernel(const int* __restrict__ bsum,
                             int* __restrict__ rowptr, int* __restrict__ cursor)
{
    int i = blockIdx.x * 256 + threadIdx.x;
    if (i < NDST) {
        int v = rowptr[i] + bsum[i >> 10];
        rowptr[i] = v;
        cursor[i] = v;
    }
}

__global__ void scatter_kernel(const int* __restrict__ ei,
                               int* __restrict__ cursor, int* __restrict__ eids)
{
    int e = blockIdx.x * 256 + threadIdx.x;
    if (e < NE) {
        int pos = atomicAdd(&cursor[ei[NE + e]], 1);
        eids[pos] = e;
    }
}

// ---------------------------------------------------------------------------
// edge_score2: 128 edges x 128 cols per block, 8x8 micro-tile, fused
// tanh-dot + s1[src]+s2[dst]+battn. eaS padded (9 f4/row) vs 4-way bank hits.
// Thread covers cols [4cg..4cg+4) and [64+4cg..64+4cg+4).
// ---------------------------------------------------------------------------
__global__ __launch_bounds__(256) void edge_score2_kernel(
    const int* __restrict__ ei, const float* __restrict__ eattr,
    const float* __restrict__ We, const float* __restrict__ be,
    const float* __restrict__ wattn, const float* __restrict__ battn,
    const float* __restrict__ s1, const float* __restrict__ s2,
    float* __restrict__ scores)
{
    __shared__ float eaS[128 * 36];    // 18KB, row stride 9 f4
    __shared__ float WeS[EDIM * HD];   // 16KB
    const int t = threadIdx.x;
    const int e0 = blockIdx.x * 128;
    float4* eaSp = (float4*)eaS;
    float4* WeS4 = (float4*)WeS;
    const float4* ea_g4 = (const float4*)eattr;
    const float4* We_g4 = (const float4*)We;

#pragma unroll
    for (int i = 0; i < 4; ++i) {
        int idx = t + i*256;               // 0..1023: row*8+k4
        int row = idx >> 3, k4 = idx & 7;
        int e = e0 + row;
        eaSp[row*9 + k4] = (e < NE) ? ea_g4[(size_t)e*8 + k4]
                                    : make_float4(0.f,0.f,0.f,0.f);
    }
#pragma unroll
    for (int i = 0; i < 4; ++i) WeS4[t + i*256] = We_g4[t + i*256];
    __syncthreads();

    const int cg = t & 15;                 // 16 col groups
    const int rg = t >> 4;                 // 16 row groups x 8 rows

    const float4 beA = ((const float4*)be)[cg];
    const float4 beB = ((const float4*)be)[cg + 16];
    float4 acc[8][2];
#pragma unroll
    for (int r = 0; r < 8; ++r) { acc[r][0] = beA; acc[r][1] = beB; }

#pragma unroll
    for (int k4 = 0; k4 < 8; ++k4) {
        float4 w0[4], w1[4];
#pragma unroll
        for (int kk = 0; kk < 4; ++kk) {
            w0[kk] = WeS4[(k4*4 + kk)*32 + cg];
            w1[kk] = WeS4[(k4*4 + kk)*32 + cg + 16];
        }
#pragma unroll
        for (int r = 0; r < 8; ++r) {
            float4 a = eaSp[(rg*8 + r)*9 + k4];
            acc[r][0].x += a.x*w0[0].x + a.y*w0[1].x + a.z*w0[2].x + a.w*w0[3].x;
            acc[r][0].y += a.x*w0[0].y + a.y*w0[1].y + a.z*w0[2].y + a.w*w0[3].y;
            acc[r][0].z += a.x*w0[0].z + a.y*w0[1].z + a.z*w0[2].z + a.w*w0[3].z;
            acc[r][0].w += a.x*w0[0].w + a.y*w0[1].w + a.z*w0[2].w + a.w*w0[3].w;
            acc[r][1].x += a.x*w1[0].x + a.y*w1[1].x + a.z*w1[2].x + a.w*w1[3].x;
            acc[r][1].y += a.x*w1[0].y + a.y*w1[1].y + a.z*w1[2].y + a.w*w1[3].y;
            acc[r][1].z += a.x*w1[0].z + a.y*w1[1].z + a.z*w1[2].z + a.w*w1[3].z;
            acc[r][1].w += a.x*w1[0].w + a.y*w1[1].w + a.z*w1[2].w + a.w*w1[3].w;
        }
    }

    const float4 waA = ((const float4*)(wattn + 2*HD))[cg];
    const float4 waB = ((const float4*)(wattn + 2*HD))[cg + 16];
    const float b0 = battn[0];
    float v[8];
#pragma unroll
    for (int r = 0; r < 8; ++r) {
        v[r] = fast_tanh(acc[r][0].x)*waA.x + fast_tanh(acc[r][0].y)*waA.y
             + fast_tanh(acc[r][0].z)*waA.z + fast_tanh(acc[r][0].w)*waA.w
             + fast_tanh(acc[r][1].x)*waB.x + fast_tanh(acc[r][1].y)*waB.y
             + fast_tanh(acc[r][1].z)*waB.z + fast_tanh(acc[r][1].w)*waB.w;
    }
#pragma unroll
    for (int off = 8; off; off >>= 1) {
#pragma unroll
        for (int r = 0; r < 8; ++r) v[r] += __shfl_xor(v[r], off);
    }
    if (cg == 0) {
#pragma unroll
        for (int r = 0; r < 8; ++r) {
            int e = e0 + rg*8 + r;
            if (e < NE) scores[e] = v[r] + s1[ei[e]] + s2[ei[NE + e]] + b0;
        }
    }
}

// ---------------------------------------------------------------------------
// dst_agg3: wave per dst; softmax passes lane-parallel; accumulate pass
// processes 4 edges/iteration (lane = el*16 + c, 16 lanes x 32B per row).
// aggS[d] = sum alpha*srcmsg[src]; wea[d] = sum alpha*ea. Empty: aggS=-c2.
// ---------------------------------------------------------------------------
__global__ __launch_bounds__(256) void dst_agg3_kernel(
    const int* __restrict__ ei, const float* __restrict__ eattr,
    const int* __restrict__ rowptr, const int* __restrict__ eids,
    const float* __restrict__ scores, const float* __restrict__ srcmsg,
    const float* __restrict__ c2,
    float* __restrict__ aggS, float* __restrict__ wea)
{
    const int lane = threadIdx.x & 63;
    const int gw = blockIdx.x * 4 + (threadIdx.x >> 6);
    const int nw = gridDim.x * 4;
    const int el = lane >> 4;              // edge slot 0..3
    const int c  = lane & 15;              // col f4 pair index
    const float4* sm4 = (const float4*)srcmsg;
    const float2* ea2 = (const float2*)eattr;
    float4* aggS4 = (float4*)aggS;
    float2* wea2 = (float2*)wea;
    const float4* c24 = (const float4*)c2;

    for (int d = gw; d < NDST; d += nw) {
        const int start = rowptr[d], end = rowptr[d + 1];
        if (start == end) {
            if (lane < 32) {
                float4 cv = c24[lane];
                aggS4[(size_t)d*32 + lane] = make_float4(-cv.x, -cv.y, -cv.z, -cv.w);
            }
            if (lane < 8) ((float4*)wea)[(size_t)d*8 + lane] = make_float4(0.f,0.f,0.f,0.f);
            continue;
        }
        float m = -3.4e38f;
        for (int i = start + lane; i < end; i += 64)
            m = fmaxf(m, scores[eids[i]]);
#pragma unroll
        for (int off = 32; off; off >>= 1) m = fmaxf(m, __shfl_xor(m, off));

        float s = 0.f;
        for (int i = start + lane; i < end; i += 64)
            s += __expf(scores[eids[i]] - m);
#pragma unroll
        for (int off = 32; off; off >>= 1) s += __shfl_xor(s, off);
        const float inv = 1.f / s;

        float4 a0 = make_float4(0.f,0.f,0.f,0.f);
        float4 a1 = make_float4(0.f,0.f,0.f,0.f);
        float wx = 0.f, wy = 0.f;
        for (int i0 = start; i0 < end; i0 += 4) {
            int i = i0 + el;
            bool val = (i < end);
            int e = eids[val ? i : (end - 1)];
            float sc = scores[e];
            float w = val ? __expf(sc - m) : 0.f;
            int src = ei[e];
            const float4* row = sm4 + (size_t)src * 32;
            float4 r0 = row[2*c];
            float4 r1 = row[2*c + 1];
            float2 ea = ea2[(size_t)e*16 + c];
            a0.x += w*r0.x; a0.y += w*r0.y; a0.z += w*r0.z; a0.w += w*r0.w;
            a1.x += w*r1.x; a1.y += w*r1.y; a1.z += w*r1.z; a1.w += w*r1.w;
            wx += w*ea.x; wy += w*ea.y;
        }
        // reduce across the 4 edge slots (lane bits 4,5)
#pragma unroll
        for (int off = 16; off <= 32; off <<= 1) {
            a0.x += __shfl_xor(a0.x, off); a0.y += __shfl_xor(a0.y, off);
            a0.z += __shfl_xor(a0.z, off); a0.w += __shfl_xor(a0.w, off);
            a1.x += __shfl_xor(a1.x, off); a1.y += __shfl_xor(a1.y, off);
            a1.z += __shfl_xor(a1.z, off); a1.w += __shfl_xor(a1.w, off);
            wx += __shfl_xor(wx, off); wy += __shfl_xor(wy, off);
        }
        if (lane < 16) {
            aggS4[(size_t)d*32 + 2*c]     = make_float4(a0.x*inv, a0.y*inv, a0.z*inv, a0.w*inv);
            aggS4[(size_t)d*32 + 2*c + 1] = make_float4(a1.x*inv, a1.y*inv, a1.z*inv, a1.w*inv);
            wea2[(size_t)d*16 + c] = make_float2(wx*inv, wy*inv);
        }
    }
}

// ---------------------------------------------------------------------------
// out_ln: out = LN(tmp + wea@W3) * gamma + beta
// (tmp already holds dstx@(I+Wout1) + aggS@Wout2 + bias2)
// ---------------------------------------------------------------------------
__global__ __launch_bounds__(256) void out_ln_kernel(
    const float* __restrict__ tmp, const float* __restrict__ wea,
    const float* __restrict__ W3, const float* __restrict__ gamma,
    const float* __restrict__ beta, float* __restrict__ out, int N)
{
    __shared__ float As[32 * 32];      // wea tile, 4KB
    __shared__ float Ws[EDIM * HD];    // 16KB
    const int t = threadIdx.x;
    const int cg = t & 31;
    const int rg = t >> 5;             // 8 groups x 4 rows
    const int row0 = blockIdx.x * 32;
    float4* As4 = (float4*)As;
    float4* Ws4 = (float4*)Ws;
    const float4* weag4 = (const float4*)wea;
    const float4* W3g4 = (const float4*)W3;
    const float4* tmp4 = (const float4*)tmp;
    float4* out4 = (float4*)out;
    const int maxAf4 = N * 8;

    {
        int row = t >> 3, k4 = t & 7;
        int g = (row0 + row)*8 + k4;
        As4[t] = (g < maxAf4) ? weag4[g] : make_float4(0.f,0.f,0.f,0.f);
    }
#pragma unroll
    for (int i = 0; i < 4; ++i) Ws4[t + i*256] = W3g4[t + i*256];
    __syncthreads();

    float4 acc[4];
#pragma unroll
    for (int rr = 0; rr < 4; ++rr) {
        int r = row0 + rg*4 + rr;
        r = (r < N) ? r : (N - 1);
        acc[rr] = tmp4[r*32 + cg];
    }

#pragma unroll
    for (int k4 = 0; k4 < 8; ++k4) {
        float4 w[4];
#pragma unroll
        for (int kk = 0; kk < 4; ++kk) w[kk] = Ws4[(k4*4 + kk)*32 + cg];
#pragma unroll
        for (int rr = 0; rr < 4; ++rr) {
            float4 a = As4[(rg*4 + rr)*8 + k4];
            acc[rr].x += a.x*w[0].x + a.y*w[1].x + a.z*w[2].x + a.w*w[3].x;
            acc[rr].y += a.x*w[0].y + a.y*w[1].y + a.z*w[2].y + a.w*w[3].y;
            acc[rr].z += a.x*w[0].z + a.y*w[1].z + a.z*w[2].z + a.w*w[3].z;
            acc[rr].w += a.x*w[0].w + a.y*w[1].w + a.z*w[2].w + a.w*w[3].w;
        }
    }

    const float4 g4 = ((const float4*)gamma)[cg];
    const float4 b4 = ((const float4*)beta)[cg];
#pragma unroll
    for (int rr = 0; rr < 4; ++rr) {
        float s = acc[rr].x + acc[rr].y + acc[rr].z + acc[rr].w;
        float q = acc[rr].x*acc[rr].x + acc[rr].y*acc[rr].y
                + acc[rr].z*acc[rr].z + acc[rr].w*acc[rr].w;
#pragma unroll
        for (int off = 1; off <= 16; off <<= 1) {
            s += __shfl_xor(s, off);
            q += __shfl_xor(q, off);
        }
        const float mean = s * (1.f / HD);
        const float var  = q * (1.f / HD) - mean * mean;
        const float rstd = rsqrtf(var + LN_EPS);
        int r = row0 + rg*4 + rr;
        if (r < N) {
            float4 o;
            o.x = (acc[rr].x - mean) * rstd * g4.x + b4.x;
            o.y = (acc[rr].y - mean) * rstd * g4.y + b4.y;
            o.z = (acc[rr].z - mean) * rstd * g4.z + b4.z;
            o.w = (acc[rr].w - mean) * rstd * g4.w + b4.w;
            out4[r*32 + cg] = o;
        }
    }
}

// ---------------------------------------------------------------------------
extern "C" void kernel_launch(void* const* d_in, const int* in_sizes, int n_in,
                              void* d_out, int out_size, void* d_ws, size_t ws_size,
                              hipStream_t stream)
{
    const float* src_x = (const float*)d_in[0];
    const float* dst_x = (const float*)d_in[1];
    const int*   ei    = (const int*)d_in[2];
    const float* eattr = (const float*)d_in[3];
    const float* Wsrc  = (const float*)d_in[4];
    const float* bsrc  = (const float*)d_in[5];
    const float* Wdst  = (const float*)d_in[6];
    const float* bdst  = (const float*)d_in[7];
    const float* We    = (const float*)d_in[8];
    const float* be    = (const float*)d_in[9];
    const float* Wattn = (const float*)d_in[10];
    const float* battn = (const float*)d_in[11];
    const float* Wmsg  = (const float*)d_in[12];
    const float* bmsg  = (const float*)d_in[13];
    const float* Wout  = (const float*)d_in[14];
    const float* bout  = (const float*)d_in[15];
    const float* gamma = (const float*)d_in[16];
    const float* beta  = (const float*)d_in[17];
    float* out = (float*)d_out;

    float* ws     = (float*)d_ws;
    float* srcmsg = ws;                        // 6,400,000 (aliased by tmp later)
    float* tmp    = ws;
    float* aggS   = ws + 6400000;
    float* wea    = ws + 12800000;             // 1,600,000
    float* s1     = ws + 14400000;
    float* s2     = ws + 14450048;
    float* scores = ws + 14500096;
    float* Wsm    = ws + 15000096;
    float* bsm    = ws + 15016480;
    float* WeMsg  = ws + 15016608;
    float* c2     = ws + 15020704;
    float* W3     = ws + 15020832;
    float* bias2  = ws + 15024928;
    float* Wout1p = ws + 15025056;             // 16,384
    int* rowptr   = (int*)(ws + 15041440);     // 50,016
    int* cursor   = rowptr + 50016;            // 50,016
    int* eids     = cursor + 50016;            // 500,000
    int* bsum     = eids + 500000;             // 64

    hipMemsetAsync(cursor, 0, NDST * sizeof(int), stream);

    fold1_kernel<<<162, 128, 0, stream>>>(Wsrc, bsrc, We, be, Wmsg, bmsg,
                                          Wsm, bsm, WeMsg, c2);
    fold2_kernel<<<161, 128, 0, stream>>>(WeMsg, c2, Wout, bout, W3, bias2, Wout1p);

    const int g64 = (NSRC + 63) / 64;          // 782

    gemm_td_v3_kernel<<<g64, 256, 0, stream>>>(src_x, Wsrc, bsrc, Wattn, s1, NSRC);
    gemm_td_v3_kernel<<<g64, 256, 0, stream>>>(dst_x, Wdst, bdst, Wattn + HD, s2, NDST);
    gemm128_v3_kernel<<<g64, 256, 0, stream>>>(src_x, Wsm, bsm, srcmsg, NSRC, 0);

    hist_kernel<<<(NE + 255) / 256, 256, 0, stream>>>(ei, cursor);
    scan1_kernel<<<(NDST + 1023) / 1024, 1024, 0, stream>>>(cursor, rowptr, bsum);
    scan2_kernel<<<1, 64, 0, stream>>>(bsum, rowptr);
    scan3_kernel<<<(NDST + 255) / 256, 256, 0, stream>>>(bsum, rowptr, cursor);
    scatter_kernel<<<(NE + 255) / 256, 256, 0, stream>>>(ei, cursor, eids);

    edge_score2_kernel<<<(NE + 127) / 128, 256, 0, stream>>>(
        ei, eattr, We, be, Wattn, battn, s1, s2, scores);

    dst_agg3_kernel<<<3125, 256, 0, stream>>>(ei, eattr, rowptr, eids, scores,
                                              srcmsg, c2, aggS, wea);

    gemm128_v3_kernel<<<g64, 256, 0, stream>>>(dst_x, Wout1p, bias2, tmp, NDST, 0);
    gemm128_v3_kernel<<<g64, 256, 0, stream>>>(aggS, Wout + HD*HD, nullptr, tmp, NDST, 1);
    out_ln_kernel<<<(NDST + 31) / 32, 256, 0, stream>>>(tmp, wea, W3, gamma, beta,
                                                        out, NDST);
}

// Round 4
// 388.439 us; speedup vs baseline: 2.8996x; 1.7763x over previous
//
#include <hip/hip_runtime.h>
#include <math.h>

#define NSRC 50000
#define NDST 50000
#define NE   500000
#define HD   128
#define EDIM 32
#define LN_EPS 1e-5f

typedef __attribute__((ext_vector_type(8))) short short8;   // 8 bf16 = 4 VGPR
typedef __attribute__((ext_vector_type(4))) float f32x4;
typedef unsigned short u16;

__device__ __forceinline__ float fast_tanh(float x) {
    float e = __expf(2.f * x);
    return 1.f - 2.f / (e + 1.f);
}
__device__ __forceinline__ u16 f2b(float x) {           // f32 -> bf16 RNE
    unsigned u = __float_as_uint(x);
    return (u16)((u + 0x7FFFu + ((u >> 16) & 1u)) >> 16);
}
__device__ __forceinline__ float b2f(u16 h) {
    return __uint_as_float(((unsigned)h) << 16);
}
__device__ __forceinline__ short8 ld8(const u16* p) { return *(const short8*)p; }

// ---------------------------------------------------------------------------
// fold1: Wsm = Wsrc@Wmsg, bsm = bsrc@Wmsg + bmsg, WeMsg = We@Wmsg, c2 = be@Wmsg
// ---------------------------------------------------------------------------
__global__ __launch_bounds__(128) void fold1_kernel(
    const float* __restrict__ Wsrc, const float* __restrict__ bsrc,
    const float* __restrict__ We,   const float* __restrict__ be,
    const float* __restrict__ Wmsg, const float* __restrict__ bmsg,
    float* __restrict__ Wsm, float* __restrict__ bsm,
    float* __restrict__ WeMsg, float* __restrict__ c2)
{
    const int j = threadIdx.x;
    const int r = blockIdx.x;
    float s = 0.f;
    if (r < 128) {
        for (int k = 0; k < 128; ++k) s += Wsrc[r*HD + k] * Wmsg[k*HD + j];
        Wsm[r*HD + j] = s;
    } else if (r < 160) {
        const int rr = r - 128;
        for (int k = 0; k < 128; ++k) s += We[rr*HD + k] * Wmsg[k*HD + j];
        WeMsg[rr*HD + j] = s;
    } else if (r == 160) {
        for (int k = 0; k < 128; ++k) s += bsrc[k] * Wmsg[k*HD + j];
        bsm[j] = s + bmsg[j];
    } else {
        for (int k = 0; k < 128; ++k) s += be[k] * Wmsg[k*HD + j];
        c2[j] = s;
    }
}

// ---------------------------------------------------------------------------
// fold2: W3 = WeMsg@Wout2; bias2 = bout + c2@Wout2; Wout1p = Wout1 + I
// ---------------------------------------------------------------------------
__global__ __launch_bounds__(128) void fold2_kernel(
    const float* __restrict__ WeMsg, const float* __restrict__ c2,
    const float* __restrict__ Wout, const float* __restrict__ bout,
    float* __restrict__ W3, float* __restrict__ bias2,
    float* __restrict__ Wout1p)
{
    const int j = threadIdx.x;
    const int r = blockIdx.x;
    const float* Wout2 = Wout + HD*HD;
    if (r < 32) {
        float s = 0.f;
        for (int k = 0; k < 128; ++k) s += WeMsg[r*HD + k] * Wout2[k*HD + j];
        W3[r*HD + j] = s;
    } else if (r == 32) {
        float s = 0.f;
        for (int k = 0; k < 128; ++k) s += c2[k] * Wout2[k*HD + j];
        bias2[j] = s + bout[j];
    } else {
        const int rr = r - 33;
        Wout1p[rr*HD + j] = Wout[rr*HD + j] + ((rr == j) ? 1.f : 0.f);
    }
}

// ---------------------------------------------------------------------------
// pack_all: pack f32 [K x 128] weights into bf16 MFMA B-fragment layout:
//   dst[((kc*8 + t)*64 + lane)*8 + j] = bf16(src[(kc*32 + (lane>>4)*8 + j)*128 + t*16 + (lane&15)])
// blocks: Wsrc 0-31, Wdst 32-63, Wsm 64-95, Wout1p 96-127, Wout2 128-159,
//         We 160-167 (K=32), W3 168-175 (K=32). 64 threads/block.
// ---------------------------------------------------------------------------
__global__ __launch_bounds__(64) void pack_all_kernel(
    const float* __restrict__ Wsrc, const float* __restrict__ Wdst,
    const float* __restrict__ Wsm,  const float* __restrict__ Wout1p,
    const float* __restrict__ Wout2,const float* __restrict__ We,
    const float* __restrict__ W3,
    u16* __restrict__ Wsrc_pk, u16* __restrict__ Wdst_pk,
    u16* __restrict__ Wsm_pk,  u16* __restrict__ W1_pk,
    u16* __restrict__ W2_pk,   u16* __restrict__ We_pk,
    u16* __restrict__ W3_pk)
{
    const int b = blockIdx.x;
    const int lane = threadIdx.x;
    const float* src; u16* dst; int lb;
    if      (b < 32)  { src = Wsrc;   dst = Wsrc_pk; lb = b; }
    else if (b < 64)  { src = Wdst;   dst = Wdst_pk; lb = b - 32; }
    else if (b < 96)  { src = Wsm;    dst = Wsm_pk;  lb = b - 64; }
    else if (b < 128) { src = Wout1p; dst = W1_pk;   lb = b - 96; }
    else if (b < 160) { src = Wout2;  dst = W2_pk;   lb = b - 128; }
    else if (b < 168) { src = We;     dst = We_pk;   lb = b - 160; }
    else              { src = W3;     dst = W3_pk;   lb = b - 168; }
    const int kc = lb >> 3, t = lb & 7;
    const int ln = lane & 15, quad = lane >> 4;
    u16 tmp[8];
#pragma unroll
    for (int j = 0; j < 8; ++j)
        tmp[j] = f2b(src[(kc*32 + quad*8 + j)*HD + t*16 + ln]);
    *(short8*)(dst + (size_t)(lb*64 + lane)*8) = *(short8*)tmp;
}

// ---------------------------------------------------------------------------
// convert: f32 -> bf16 for src_x, dst_x, edge_attr (4 elems/thread)
// ---------------------------------------------------------------------------
__global__ __launch_bounds__(256) void convert_kernel(
    const float* __restrict__ sx, const float* __restrict__ dx,
    const float* __restrict__ ea,
    u16* __restrict__ sxb, u16* __restrict__ dxb, u16* __restrict__ eab)
{
    const int n0 = NSRC*HD/4, n1 = n0 + NDST*HD/4, n2 = n1 + NE*EDIM/4;
    int i = blockIdx.x * 256 + threadIdx.x;
    const float4* s4; u16* d; int base;
    if (i < n0)      { s4 = (const float4*)sx; d = sxb; base = i; }
    else if (i < n1) { s4 = (const float4*)dx; d = dxb; base = i - n0; }
    else if (i < n2) { s4 = (const float4*)ea; d = eab; base = i - n1; }
    else return;
    float4 v = s4[base];
    u16 o[4] = { f2b(v.x), f2b(v.y), f2b(v.z), f2b(v.w) };
    *(ushort4*)(d + (size_t)base*4) = *(ushort4*)o;
}

// ---------------------------------------------------------------------------
// node_gemm: per 16 src rows (1 wave): s1 = tanhdot(sxb@Wsrc+bsrc, wa1) and
// srcmsgb = bf16(sxb@Wsm + bsm). MFMA 16x16x32, B-frags from packed global.
// ---------------------------------------------------------------------------
__global__ __launch_bounds__(256) void node_gemm_kernel(
    const u16* __restrict__ sxb, const u16* __restrict__ Wsrc_pk,
    const u16* __restrict__ Wsm_pk, const float* __restrict__ bsrc,
    const float* __restrict__ bsm, const float* __restrict__ wa1,
    float* __restrict__ s1, u16* __restrict__ srcmsgb)
{
    __shared__ u16 lds[4 * 16 * HD];     // 16 KB, one 16x128 slab per wave
    const int t = threadIdx.x;
    const int w = t >> 6, lane = t & 63;
    const int ln = lane & 15, quad = lane >> 4;
    int row0 = (blockIdx.x * 4 + w) * 16;
    if (row0 > NSRC - 16) row0 = NSRC - 16;      // clamp (dup writes benign)

    short8 a[4];
#pragma unroll
    for (int kc = 0; kc < 4; ++kc)
        a[kc] = ld8(sxb + (size_t)(row0 + ln)*HD + kc*32 + quad*8);

    // ---- s1 path
    float v[4] = {0.f, 0.f, 0.f, 0.f};
#pragma unroll
    for (int tt = 0; tt < 8; ++tt) {
        f32x4 acc = {0.f, 0.f, 0.f, 0.f};
#pragma unroll
        for (int kc = 0; kc < 4; ++kc) {
            short8 b = ld8(Wsrc_pk + (size_t)((kc*8 + tt)*64 + lane)*8);
            acc = __builtin_amdgcn_mfma_f32_16x16x32_bf16(a[kc], b, acc, 0, 0, 0);
        }
        const float bb = bsrc[tt*16 + ln];
        const float ww = wa1[tt*16 + ln];
#pragma unroll
        for (int r = 0; r < 4; ++r) v[r] += fast_tanh(acc[r] + bb) * ww;
    }
#pragma unroll
    for (int off = 8; off >= 1; off >>= 1)
#pragma unroll
        for (int r = 0; r < 4; ++r) v[r] += __shfl_xor(v[r], off);
    if (ln == 0) {
#pragma unroll
        for (int r = 0; r < 4; ++r) s1[row0 + quad*4 + r] = v[r];
    }

    // ---- srcmsg path
#pragma unroll
    for (int tt = 0; tt < 8; ++tt) {
        f32x4 acc = {0.f, 0.f, 0.f, 0.f};
#pragma unroll
        for (int kc = 0; kc < 4; ++kc) {
            short8 b = ld8(Wsm_pk + (size_t)((kc*8 + tt)*64 + lane)*8);
            acc = __builtin_amdgcn_mfma_f32_16x16x32_bf16(a[kc], b, acc, 0, 0, 0);
        }
        const float bb = bsm[tt*16 + ln];
#pragma unroll
        for (int r = 0; r < 4; ++r)
            lds[w*2048 + (quad*4 + r)*HD + tt*16 + ln] = f2b(acc[r] + bb);
    }
    __syncthreads();
#pragma unroll
    for (int r = 0; r < 4; ++r) {
        int idx = r*512 + lane*8;
        short8 val = *(short8*)(lds + w*2048 + idx);
        int row = idx >> 7, col = idx & 127;
        *(short8*)(srcmsgb + (size_t)(row0 + row)*HD + col) = val;
    }
}

// ---------------------------------------------------------------------------
// dst_gemm: s2 = tanhdot(dxb@Wdst+bdst, wa2) per 16 rows / wave
// ---------------------------------------------------------------------------
__global__ __launch_bounds__(256) void dst_gemm_kernel(
    const u16* __restrict__ dxb, const u16* __restrict__ Wdst_pk,
    const float* __restrict__ bdst, const float* __restrict__ wa2,
    float* __restrict__ s2)
{
    const int t = threadIdx.x;
    const int w = t >> 6, lane = t & 63;
    const int ln = lane & 15, quad = lane >> 4;
    int row0 = (blockIdx.x * 4 + w) * 16;
    if (row0 > NDST - 16) row0 = NDST - 16;

    short8 a[4];
#pragma unroll
    for (int kc = 0; kc < 4; ++kc)
        a[kc] = ld8(dxb + (size_t)(row0 + ln)*HD + kc*32 + quad*8);

    float v[4] = {0.f, 0.f, 0.f, 0.f};
#pragma unroll
    for (int tt = 0; tt < 8; ++tt) {
        f32x4 acc = {0.f, 0.f, 0.f, 0.f};
#pragma unroll
        for (int kc = 0; kc < 4; ++kc) {
            short8 b = ld8(Wdst_pk + (size_t)((kc*8 + tt)*64 + lane)*8);
            acc = __builtin_amdgcn_mfma_f32_16x16x32_bf16(a[kc], b, acc, 0, 0, 0);
        }
        const float bb = bdst[tt*16 + ln];
        const float ww = wa2[tt*16 + ln];
#pragma unroll
        for (int r = 0; r < 4; ++r) v[r] += fast_tanh(acc[r] + bb) * ww;
    }
#pragma unroll
    for (int off = 8; off >= 1; off >>= 1)
#pragma unroll
        for (int r = 0; r < 4; ++r) v[r] += __shfl_xor(v[r], off);
    if (ln == 0) {
#pragma unroll
        for (int r = 0; r < 4; ++r) s2[row0 + quad*4 + r] = v[r];
    }
}

// ---------------------------------------------------------------------------
// CSR build
// ---------------------------------------------------------------------------
__global__ void hist_kernel(const int* __restrict__ ei, int* __restrict__ cnt)
{
    int e = blockIdx.x * 256 + threadIdx.x;
    if (e < NE) atomicAdd(&cnt[ei[NE + e]], 1);
}

__global__ __launch_bounds__(1024) void scan1_kernel(
    const int* __restrict__ cnt, int* __restrict__ excl, int* __restrict__ bsum)
{
    __shared__ int buf[1024];
    const int t = threadIdx.x;
    const int i = blockIdx.x * 1024 + t;
    int v = (i < NDST) ? cnt[i] : 0;
    buf[t] = v;
    __syncthreads();
    for (int off = 1; off < 1024; off <<= 1) {
        int tv = (t >= off) ? buf[t - off] : 0;
        __syncthreads();
        buf[t] += tv;
        __syncthreads();
    }
    if (i < NDST) excl[i] = buf[t] - v;
    if (t == 1023) bsum[blockIdx.x] = buf[1023];
}

__global__ void scan2_kernel(int* __restrict__ bsum, int* __restrict__ rowptr)
{
    const int NB = (NDST + 1023) / 1024;
    const int t = threadIdx.x;
    int orig = (t < NB) ? bsum[t] : 0;
    int v = orig;
    for (int off = 1; off < 64; off <<= 1) {
        int u = __shfl_up(v, off);
        if (t >= off) v += u;
    }
    int total = __shfl(v, 63);
    if (t < NB) bsum[t] = v - orig;
    if (t == 0) rowptr[NDST] = total;
}

__global__ void scan3_kernel(const int* __restrict__ bsum,
                             int* __restrict__ rowptr, int* __restrict__ cursor)
{
    int i = blockIdx.x * 256 + threadIdx.x;
    if (i < NDST) {
        int v = rowptr[i] + bsum[i >> 10];
        rowptr[i] = v;
        cursor[i] = v;
    }
}

// scatter: ev[pos] = (src, e); epos[e] = pos (sequential write)
__global__ void scatter_kernel(const int* __restrict__ ei,
                               int* __restrict__ cursor,
                               int2* __restrict__ ev, int* __restrict__ epos)
{
    int e = blockIdx.x * 256 + threadIdx.x;
    if (e < NE) {
        int pos = atomicAdd(&cursor[ei[NE + e]], 1);
        ev[pos] = make_int2(ei[e], e);
        epos[e] = pos;
    }
}

// ---------------------------------------------------------------------------
// edge_score_mfma: 16 edges / wave. score = tanhdot(ea@We+be, wa3)
//                  + s1[src] + s2[dst] + battn, written to score_s[epos[e]].
// ---------------------------------------------------------------------------
__global__ __launch_bounds__(256) void edge_score_mfma_kernel(
    const int* __restrict__ ei, const u16* __restrict__ eab,
    const u16* __restrict__ We_pk, const float* __restrict__ be,
    const float* __restrict__ wattn, const float* __restrict__ battn,
    const float* __restrict__ s1, const float* __restrict__ s2,
    const int* __restrict__ epos, float* __restrict__ score_s)
{
    const int t = threadIdx.x;
    const int w = t >> 6, lane = t & 63;
    const int ln = lane & 15, quad = lane >> 4;
    const int e0 = (blockIdx.x * 4 + w) * 16;
    if (e0 >= NE) return;                  // NE%16==0, no partial tiles

    short8 a = ld8(eab + (size_t)(e0 + ln)*EDIM + quad*8);
    const float* wa3 = wattn + 2*HD;

    float v[4] = {0.f, 0.f, 0.f, 0.f};
#pragma unroll
    for (int tt = 0; tt < 8; ++tt) {
        short8 b = ld8(We_pk + (size_t)(tt*64 + lane)*8);
        f32x4 acc = {0.f, 0.f, 0.f, 0.f};
        acc = __builtin_amdgcn_mfma_f32_16x16x32_bf16(a, b, acc, 0, 0, 0);
        const float bb = be[tt*16 + ln];
        const float ww = wa3[tt*16 + ln];
#pragma unroll
        for (int r = 0; r < 4; ++r) v[r] += fast_tanh(acc[r] + bb) * ww;
    }
#pragma unroll
    for (int off = 8; off >= 1; off >>= 1)
#pragma unroll
        for (int r = 0; r < 4; ++r) v[r] += __shfl_xor(v[r], off);

    if (ln == 0) {
        const float b0 = battn[0];
#pragma unroll
        for (int r = 0; r < 4; ++r) {
            int e = e0 + quad*4 + r;
            score_s[epos[e]] = v[r] + s1[ei[e]] + s2[ei[NE + e]] + b0;
        }
    }
}

// ---------------------------------------------------------------------------
// dst_agg4: 1 wave per dst. Sequential score_s/ev reads; 4 edges in flight;
// 16 lanes x 16B cover one bf16 srcmsg row. Outputs aggSb (bf16 [NDST,128])
// and weab (bf16 [NDST,32]). Empty dst: aggSb = bf16(-c2), weab = 0.
// ---------------------------------------------------------------------------
__global__ __launch_bounds__(256) void dst_agg4_kernel(
    const int2* __restrict__ ev, const int* __restrict__ rowptr,
    const float* __restrict__ score_s, const u16* __restrict__ srcmsgb,
    const u16* __restrict__ eab, const float* __restrict__ c2,
    u16* __restrict__ aggSb, u16* __restrict__ weab)
{
    const int lane = threadIdx.x & 63;
    const int d = blockIdx.x * 4 + (threadIdx.x >> 6);
    const int el = lane >> 4, c = lane & 15;
    const int start = rowptr[d], end = rowptr[d + 1];

    if (start == end) {
        if (el == 0) {
            u16 z[8];
#pragma unroll
            for (int j = 0; j < 8; ++j) z[j] = f2b(-c2[c*8 + j]);
            *(short8*)(aggSb + (size_t)d*HD + c*8) = *(short8*)z;
            if (c < 4) {
                u16 zz[8] = {0,0,0,0,0,0,0,0};
                *(short8*)(weab + (size_t)d*EDIM + c*8) = *(short8*)zz;
            }
        }
        return;
    }

    float m = -3.4e38f;
    for (int i = start + lane; i < end; i += 64) m = fmaxf(m, score_s[i]);
#pragma unroll
    for (int off = 32; off; off >>= 1) m = fmaxf(m, __shfl_xor(m, off));

    float s = 0.f;
    for (int i = start + lane; i < end; i += 64) s += __expf(score_s[i] - m);
#pragma unroll
    for (int off = 32; off; off >>= 1) s += __shfl_xor(s, off);
    const float inv = 1.f / s;

    float acc[8] = {0,0,0,0,0,0,0,0};
    float wacc[8] = {0,0,0,0,0,0,0,0};
    for (int i0 = start; i0 < end; i0 += 4) {
        int i = i0 + el;
        bool val = (i < end);
        int ii = val ? i : start;
        int2 se = ev[ii];
        float w = val ? __expf(score_s[ii] - m) : 0.f;
        short8 sm = ld8(srcmsgb + (size_t)se.x*HD + c*8);
#pragma unroll
        for (int j = 0; j < 8; ++j) acc[j] += w * b2f(((u16*)&sm)[j]);
        if (c < 4) {
            short8 eav = ld8(eab + (size_t)se.y*EDIM + c*8);
#pragma unroll
            for (int j = 0; j < 8; ++j) wacc[j] += w * b2f(((u16*)&eav)[j]);
        }
    }
#pragma unroll
    for (int off = 16; off <= 32; off <<= 1) {
#pragma unroll
        for (int j = 0; j < 8; ++j) {
            acc[j]  += __shfl_xor(acc[j],  off);
            wacc[j] += __shfl_xor(wacc[j], off);
        }
    }
    if (el == 0) {
        u16 o[8];
#pragma unroll
        for (int j = 0; j < 8; ++j) o[j] = f2b(acc[j] * inv);
        *(short8*)(aggSb + (size_t)d*HD + c*8) = *(short8*)o;
        if (c < 4) {
            u16 o2[8];
#pragma unroll
            for (int j = 0; j < 8; ++j) o2[j] = f2b(wacc[j] * inv);
            *(short8*)(weab + (size_t)d*EDIM + c*8) = *(short8*)o2;
        }
    }
}

// ---------------------------------------------------------------------------
// final: out = LN(dxb@W1p + aggSb@Wout2 + weab@W3 + bias2) * gamma + beta
// per 16 dst rows / wave, 72 MFMA + LN epilogue.
// ---------------------------------------------------------------------------
__global__ __launch_bounds__(256) void final_kernel(
    const u16* __restrict__ dxb, const u16* __restrict__ aggSb,
    const u16* __restrict__ weab,
    const u16* __restrict__ W1_pk, const u16* __restrict__ W2_pk,
    const u16* __restrict__ W3_pk, const float* __restrict__ bias2,
    const float* __restrict__ gamma, const float* __restrict__ beta,
    float* __restrict__ out)
{
    const int t = threadIdx.x;
    const int w = t >> 6, lane = t & 63;
    const int ln = lane & 15, quad = lane >> 4;
    int row0 = (blockIdx.x * 4 + w) * 16;
    if (row0 > NDST - 16) row0 = NDST - 16;

    short8 a1[4], a2[4], a3;
#pragma unroll
    for (int kc = 0; kc < 4; ++kc) {
        a1[kc] = ld8(dxb   + (size_t)(row0 + ln)*HD + kc*32 + quad*8);
        a2[kc] = ld8(aggSb + (size_t)(row0 + ln)*HD + kc*32 + quad*8);
    }
    a3 = ld8(weab + (size_t)(row0 + ln)*EDIM + quad*8);

    f32x4 accs[8];
#pragma unroll
    for (int tt = 0; tt < 8; ++tt) {
        f32x4 acc = {0.f, 0.f, 0.f, 0.f};
#pragma unroll
        for (int kc = 0; kc < 4; ++kc) {
            short8 b = ld8(W1_pk + (size_t)((kc*8 + tt)*64 + lane)*8);
            acc = __builtin_amdgcn_mfma_f32_16x16x32_bf16(a1[kc], b, acc, 0, 0, 0);
        }
#pragma unroll
        for (int kc = 0; kc < 4; ++kc) {
            short8 b = ld8(W2_pk + (size_t)((kc*8 + tt)*64 + lane)*8);
            acc = __builtin_amdgcn_mfma_f32_16x16x32_bf16(a2[kc], b, acc, 0, 0, 0);
        }
        {
            short8 b = ld8(W3_pk + (size_t)(tt*64 + lane)*8);
            acc = __builtin_amdgcn_mfma_f32_16x16x32_bf16(a3, b, acc, 0, 0, 0);
        }
        const float bb = bias2[tt*16 + ln];
#pragma unroll
        for (int r = 0; r < 4; ++r) acc[r] += bb;
        accs[tt] = acc;
    }

    const float gl[8] = { gamma[ln], gamma[16+ln], gamma[32+ln], gamma[48+ln],
                          gamma[64+ln], gamma[80+ln], gamma[96+ln], gamma[112+ln] };
    const float bl[8] = { beta[ln], beta[16+ln], beta[32+ln], beta[48+ln],
                          beta[64+ln], beta[80+ln], beta[96+ln], beta[112+ln] };
#pragma unroll
    for (int r = 0; r < 4; ++r) {
        float s = 0.f, q = 0.f;
#pragma unroll
        for (int tt = 0; tt < 8; ++tt) {
            float u = accs[tt][r];
            s += u; q += u*u;
        }
#pragma unroll
        for (int off = 8; off >= 1; off >>= 1) {
            s += __shfl_xor(s, off);
            q += __shfl_xor(q, off);
        }
        const float mean = s * (1.f / HD);
        const float var  = q * (1.f / HD) - mean * mean;
        const float rstd = rsqrtf(var + LN_EPS);
        const int row = row0 + quad*4 + r;
#pragma unroll
        for (int tt = 0; tt < 8; ++tt)
            out[(size_t)row*HD + tt*16 + ln] =
                (accs[tt][r] - mean) * rstd * gl[tt] + bl[tt];
    }
}

// ---------------------------------------------------------------------------
extern "C" void kernel_launch(void* const* d_in, const int* in_sizes, int n_in,
                              void* d_out, int out_size, void* d_ws, size_t ws_size,
                              hipStream_t stream)
{
    const float* src_x = (const float*)d_in[0];
    const float* dst_x = (const float*)d_in[1];
    const int*   ei    = (const int*)d_in[2];
    const float* eattr = (const float*)d_in[3];
    const float* Wsrc  = (const float*)d_in[4];
    const float* bsrc  = (const float*)d_in[5];
    const float* Wdst  = (const float*)d_in[6];
    const float* bdst  = (const float*)d_in[7];
    const float* We    = (const float*)d_in[8];
    const float* be    = (const float*)d_in[9];
    const float* Wattn = (const float*)d_in[10];
    const float* battn = (const float*)d_in[11];
    const float* Wmsg  = (const float*)d_in[12];
    const float* bmsg  = (const float*)d_in[13];
    const float* Wout  = (const float*)d_in[14];
    const float* bout  = (const float*)d_in[15];
    const float* gamma = (const float*)d_in[16];
    const float* beta  = (const float*)d_in[17];
    float* out = (float*)d_out;

    float* ws = (float*)d_ws;
    u16* sxb     = (u16*)(ws + 0);            // 6.4M bf16
    u16* dxb     = (u16*)(ws + 3200000);      // 6.4M bf16
    u16* eab     = (u16*)(ws + 6400000);      // 16M bf16
    u16* srcmsgb = (u16*)(ws + 14400000);     // 6.4M bf16
    u16* aggSb   = (u16*)(ws + 17600000);     // 6.4M bf16
    u16* weab    = (u16*)(ws + 20800000);     // 1.6M bf16
    float* s1    = ws + 21600000;
    float* s2    = ws + 21650048;
    float* score_s = ws + 21700096;           // 500000
    float* Wsm   = ws + 22200096;
    float* bsm   = ws + 22216480;
    float* WeMsg = ws + 22216608;
    float* c2    = ws + 22220704;
    float* W3    = ws + 22220832;
    float* bias2 = ws + 22224928;
    float* Wout1p= ws + 22225056;             // 16384
    u16* Wsrc_pk = (u16*)(ws + 22241440);     // 16384 u16
    u16* Wdst_pk = (u16*)(ws + 22249632);
    u16* Wsm_pk  = (u16*)(ws + 22257824);
    u16* W1_pk   = (u16*)(ws + 22266016);
    u16* W2_pk   = (u16*)(ws + 22274208);
    u16* We_pk   = (u16*)(ws + 22282400);     // 4096 u16
    u16* W3_pk   = (u16*)(ws + 22284448);
    int* rowptr  = (int*)(ws + 22286496);     // 50016
    int* cursor  = rowptr + 50016;
    int2* ev     = (int2*)(cursor + 50016);   // 500000 int2
    int* epos    = (int*)ev + 1000000;        // 500000
    int* bsum    = epos + 500000;             // 64

    hipMemsetAsync(cursor, 0, NDST * sizeof(int), stream);

    fold1_kernel<<<162, 128, 0, stream>>>(Wsrc, bsrc, We, be, Wmsg, bmsg,
                                          Wsm, bsm, WeMsg, c2);
    fold2_kernel<<<161, 128, 0, stream>>>(WeMsg, c2, Wout, bout, W3, bias2, Wout1p);
    pack_all_kernel<<<176, 64, 0, stream>>>(Wsrc, Wdst, Wsm, Wout1p, Wout + HD*HD,
                                            We, W3,
                                            Wsrc_pk, Wdst_pk, Wsm_pk, W1_pk,
                                            W2_pk, We_pk, W3_pk);
    convert_kernel<<<28125, 256, 0, stream>>>(src_x, dst_x, eattr, sxb, dxb, eab);

    const int g16 = (NSRC/16 + 3) / 4;        // 782 blocks, 4 waves each

    node_gemm_kernel<<<g16, 256, 0, stream>>>(sxb, Wsrc_pk, Wsm_pk, bsrc, bsm,
                                              Wattn, s1, srcmsgb);
    dst_gemm_kernel<<<g16, 256, 0, stream>>>(dxb, Wdst_pk, bdst, Wattn + HD, s2);

    hist_kernel<<<(NE + 255) / 256, 256, 0, stream>>>(ei, cursor);
    scan1_kernel<<<(NDST + 1023) / 1024, 1024, 0, stream>>>(cursor, rowptr, bsum);
    scan2_kernel<<<1, 64, 0, stream>>>(bsum, rowptr);
    scan3_kernel<<<(NDST + 255) / 256, 256, 0, stream>>>(bsum, rowptr, cursor);
    scatter_kernel<<<(NE + 255) / 256, 256, 0, stream>>>(ei, cursor, ev, epos);

    edge_score_mfma_kernel<<<(NE/16 + 3) / 4, 256, 0, stream>>>(
        ei, eab, We_pk, be, Wattn, battn, s1, s2, epos, score_s);

    dst_agg4_kernel<<<NDST / 4, 256, 0, stream>>>(ev, rowptr, score_s, srcmsgb,
                                                  eab, c2, aggSb, weab);

    final_kernel<<<g16, 256, 0, stream>>>(dxb, aggSb, weab, W1_pk, W2_pk, W3_pk,
                                          bias2, gamma, beta, out);
}